// Round 15
// baseline (958.403 us; speedup 1.0000x reference)
//
#include <hip/hip_runtime.h>
#include <cstddef>
#include <cstdint>

// ---------------- problem constants ----------------
#define BB   4
#define CC   256
#define HHh  128
#define WWi  256
#define HW   32768      // H*W
#define CHW  8388608    // C*H*W
#define NN   131072     // B*H*W
#define KK   19
#define MMp  10
#define RR   190        // K*M
#define RP   192

// ---------------- output offsets (floats) ----------------
#define O_LOG   2490368     // out_seg size = 4*19*128*256
#define O_TGT   27394048
#define O_PROTO 27525120

// ---------------- ws offsets (floats) ----------------
#define WS_BUF   0           // 33,554,432 : y -> z1 -> _c (in-place, [b][c][h][w])
#define WS_WPK   33554432    // 663,552 : conv 2-way split (2 x 663552 shorts)
#define WS_PPA   34217984    // 110,592 : pa 3-way split (3 x 73728 shorts) [icb][oc][36]
#define WS_PPB   34328576    // 110,592 : pb 3-way split
#define WS_PN    34439168    // 48,640  : normalized protos [190][256] f32
#define WS_PNK   34487808    // 82,944  : proto 3-way split (3 x 55296 shorts) [icb][192][36]
#define WS_T     34570752    // 3*192 sinkhorn sums
#define WS_F     34571328    // 48,640 : f accumulator
#define WS_A     34619968    // 3*192 sinkhorn row scales
#define WS_NCNT  34620544    // 192 int
#define WS_CORR  34620736    // 131,072 int
#define WS_KEY   34751808    // 131,072 int
// end = 34,882,880 floats = 139.5 MB

typedef __attribute__((ext_vector_type(8))) short bf16x8;
typedef __attribute__((ext_vector_type(4))) short s16x4;
typedef __attribute__((ext_vector_type(4))) float f32x4;

__device__ __forceinline__ void split2pack(float v0, float v1, unsigned& hp, unsigned& lp) {
  unsigned u0 = __float_as_uint(v0), u1 = __float_as_uint(v1);
  unsigned h0 = u0 & 0xffff0000u, h1 = u1 & 0xffff0000u;
  float r0 = v0 - __uint_as_float(h0);
  float r1 = v1 - __uint_as_float(h1);
  hp = (h0 >> 16) | h1;
  lp = (__float_as_uint(r0) >> 16) | (__float_as_uint(r1) & 0xffff0000u);
}

__device__ __forceinline__ void split1(float v, short& h, short& l) {
  unsigned u = __float_as_uint(v);
  unsigned hm = u & 0xffff0000u;
  float r = v - __uint_as_float(hm);
  h = (short)(hm >> 16);
  l = (short)(__float_as_uint(r) >> 16);
}

__device__ __forceinline__ void split3s(float v, short& h, short& m, short& l) {
  unsigned u = __float_as_uint(v);
  unsigned hm = u & 0xffff0000u;
  float r1 = v - __uint_as_float(hm);
  unsigned mm = __float_as_uint(r1) & 0xffff0000u;
  float r2 = r1 - __uint_as_float(mm);
  h = (short)(hm >> 16);
  m = (short)(mm >> 16);
  l = (short)(__float_as_uint(r2) >> 16);
}

__device__ __forceinline__ void split3pack2(float v0, float v1,
                                            unsigned& hp, unsigned& mp, unsigned& lp) {
  unsigned u0 = __float_as_uint(v0), u1 = __float_as_uint(v1);
  unsigned h0 = u0 & 0xffff0000u, h1 = u1 & 0xffff0000u;
  float r0 = v0 - __uint_as_float(h0);
  float r1 = v1 - __uint_as_float(h1);
  unsigned m0 = __float_as_uint(r0) & 0xffff0000u, m1 = __float_as_uint(r1) & 0xffff0000u;
  float s0 = r0 - __uint_as_float(m0);
  float s1 = r1 - __uint_as_float(m1);
  hp = (h0 >> 16) | h1;
  mp = (m0 >> 16) | m1;
  lp = (__float_as_uint(s0) >> 16) | (__float_as_uint(s1) & 0xffff0000u);
}

__device__ __forceinline__ bf16x8 ldfrag(const short* p) {
  union { bf16x8 v; s16x4 q[2]; } u;
  u.q[0] = *(const s16x4*)p;
  u.q[1] = *(const s16x4*)(p + 4);
  return u.v;
}

// ============ prototype normalize + 3-way split-pack ============
__global__ __launch_bounds__(256) void k_prep_protos(const float* __restrict__ protos,
                                                     float* __restrict__ Pn,
                                                     short* __restrict__ pnk_h,
                                                     short* __restrict__ pnk_m,
                                                     short* __restrict__ pnk_l) {
  int r = blockIdx.x, d = threadIdx.x;
  int icb = d >> 5, i = d & 31;
  int base = (icb * 192 + r) * 36;
  if (r >= RR) {       // zero pad rows 190,191
    pnk_h[base + i] = 0; pnk_m[base + i] = 0; pnk_l[base + i] = 0;
    if (i < 4) { pnk_h[base + 32 + i] = 0; pnk_m[base + 32 + i] = 0; pnk_l[base + 32 + i] = 0; }
    return;
  }
  float v = protos[r * 256 + d];
  __shared__ float red[256];
  red[d] = v * v;
  __syncthreads();
  #pragma unroll
  for (int s = 128; s > 0; s >>= 1) {
    if (d < s) red[d] += red[d + s];
    __syncthreads();
  }
  float inv = 1.f / fmaxf(sqrtf(red[0]), 1e-12f);
  float pv = v * inv;
  Pn[r * 256 + d] = pv;
  short h, m, l;
  split3s(pv, h, m, l);
  pnk_h[base + i] = h; pnk_m[base + i] = m; pnk_l[base + i] = l;
  if (i < 4) { pnk_h[base + 32 + i] = 0; pnk_m[base + 32 + i] = 0; pnk_l[base + 32 + i] = 0; }
}

// ============ conv weight 2-way split-pack ============
__global__ __launch_bounds__(256) void k_prep_wsplit(const float* __restrict__ conv_w,
                                                     short* __restrict__ wpk_h,
                                                     short* __restrict__ wpk_l) {
  int blk = blockIdx.x;             // t9*8 + icb
  int t9 = blk >> 3, icb = blk & 7;
  int oc = threadIdx.x;
  short* dh = wpk_h + ((size_t)blk * 256 + oc) * 36;
  short* dl = wpk_l + ((size_t)blk * 256 + oc) * 36;
  #pragma unroll 4
  for (int i = 0; i < 32; i++) {
    float v = conv_w[((size_t)oc * 256 + icb * 32 + i) * 9 + t9];
    short h, l;
    split1(v, h, l);
    dh[i] = h; dl[i] = l;
  }
  #pragma unroll
  for (int i = 32; i < 36; i++) { dh[i] = 0; dl[i] = 0; }
}

// ============ 1x1 weight 3-way split-pack (pa, pb) ============
__global__ __launch_bounds__(256) void k_prep_packs(const float* __restrict__ pa_w,
                                                    const float* __restrict__ pb_w,
                                                    short* __restrict__ ppa_h,
                                                    short* __restrict__ ppa_m,
                                                    short* __restrict__ ppa_l,
                                                    short* __restrict__ ppb_h,
                                                    short* __restrict__ ppb_m,
                                                    short* __restrict__ ppb_l) {
  int blk = blockIdx.x;
  const float* W;
  short *dh, *dm, *dl;
  int icb;
  if (blk < 8) { icb = blk;     W = pa_w; dh = ppa_h; dm = ppa_m; dl = ppa_l; }
  else         { icb = blk - 8; W = pb_w; dh = ppb_h; dm = ppb_m; dl = ppb_l; }
  int oc = threadIdx.x;
  size_t base = ((size_t)icb * 256 + oc) * 36;
  dh += base; dm += base; dl += base;
  #pragma unroll 4
  for (int i = 0; i < 32; i++) {
    float v = W[(size_t)oc * 256 + icb * 32 + i];
    short h, m, l;
    split3s(v, h, m, l);
    dh[i] = h; dm[i] = m; dl[i] = l;
  }
  #pragma unroll
  for (int i = 32; i < 36; i++) { dh[i] = 0; dm[i] = 0; dl[i] = 0; }
}

// ============ conv3x3 + bias + bn1 + relu : bf16x2-split MFMA ============
// r13/r14 structure; ONLY change: kw loop fully unrolled so the compiler can
// hoist next-tap B loads (L2) under current-tap MFMA. Program order of MFMAs
// unchanged -> bitwise identical output. Spill guard: WRITE_SIZE must stay 131MB.
__global__ __launch_bounds__(256, 2) void k_conv_mfma(const float* __restrict__ x,
                                                      const short* __restrict__ wpk_h,
                                                      const short* __restrict__ wpk_l,
                                                      const float* __restrict__ conv_b,
                                                      const float* __restrict__ bn_s,
                                                      const float* __restrict__ bn_b,
                                                      const float* __restrict__ bn_m,
                                                      const float* __restrict__ bn_v,
                                                      float* __restrict__ y) {
  int bid = blockIdx.x;
  int tw = bid & 15, th = (bid >> 4) & 15, b = bid >> 8;
  int h0 = th * 8, w0 = tw * 16;
  int tid = threadIdx.x;
  int lane = tid & 63, wv = tid >> 6;
  int wm = wv & 1, wn = wv >> 1;
  int l15 = lane & 15, l4 = lane >> 4;

  __shared__ short xt_h[2][10 * 18 * 36];
  __shared__ short xt_l[2][10 * 18 * 36];

  f32x4 acc[4][8];
  #pragma unroll
  for (int i = 0; i < 4; i++)
    #pragma unroll
    for (int j = 0; j < 8; j++) acc[i][j] = (f32x4){0.f, 0.f, 0.f, 0.f};

  const float* xb = x + (size_t)b * CHW;
  int boff = (wn * 128 + l15) * 36 + l4 * 8;

  auto stageA = [&](int icb, int p) {
    int ic0 = icb << 5;
    short* dh = xt_h[p];
    short* dl = xt_l[p];
    #pragma unroll 4
    for (int idx = tid; idx < 2880; idx += 256) {
      int ww = idx % 18;
      int t  = idx / 18;
      int r  = t % 10;
      int ip = t / 10;
      int hh = h0 - 1 + r, wg = w0 - 1 + ww;
      float v0 = 0.f, v1 = 0.f;
      if ((unsigned)hh < 128u && (unsigned)wg < 256u) {
        const float* px = xb + (size_t)(ic0 + 2 * ip) * HW + hh * WWi + wg;
        v0 = px[0]; v1 = px[HW];
      }
      unsigned hp, lp;
      split2pack(v0, v1, hp, lp);
      int off = (r * 18 + ww) * 36 + 2 * ip;
      *(unsigned*)&dh[off] = hp;
      *(unsigned*)&dl[off] = lp;
    }
  };

  stageA(0, 0);
  __syncthreads();

  #pragma unroll 1
  for (int icb = 0; icb < 8; ++icb) {
    int cur = icb & 1;
    if (icb < 7) stageA(icb + 1, cur ^ 1);
    const short* xa_h = xt_h[cur];
    const short* xa_l = xt_l[cur];
    #pragma unroll 1
    for (int kh = 0; kh < 3; ++kh) {
      #pragma unroll          // FULL unroll: lets compiler overlap next-tap B loads
      for (int kw = 0; kw < 3; ++kw) {
        int t9 = kh * 3 + kw;
        const short* bh_base = wpk_h + ((size_t)(t9 * 8 + icb) * 256) * 36 + boff;
        const short* bl_base = wpk_l + ((size_t)(t9 * 8 + icb) * 256) * 36 + boff;
        bf16x8 ah[4], al[4];
        #pragma unroll
        for (int mf = 0; mf < 4; ++mf) {
          int off = ((wm * 4 + mf + kh) * 18 + l15 + kw) * 36 + l4 * 8;
          ah[mf] = ldfrag(xa_h + off);
          al[mf] = ldfrag(xa_l + off);
        }
        #pragma unroll
        for (int nf = 0; nf < 8; ++nf) {
          bf16x8 bh = ldfrag(bh_base + nf * 576);
          bf16x8 bl = ldfrag(bl_base + nf * 576);
          #pragma unroll
          for (int mf = 0; mf < 4; ++mf) {
            acc[mf][nf] = __builtin_amdgcn_mfma_f32_16x16x32_bf16(ah[mf], bh, acc[mf][nf], 0, 0, 0);
            acc[mf][nf] = __builtin_amdgcn_mfma_f32_16x16x32_bf16(ah[mf], bl, acc[mf][nf], 0, 0, 0);
            acc[mf][nf] = __builtin_amdgcn_mfma_f32_16x16x32_bf16(al[mf], bh, acc[mf][nf], 0, 0, 0);
          }
        }
      }
    }
    __syncthreads();
  }
  float* yb = y + (size_t)b * CHW;
  #pragma unroll
  for (int nf = 0; nf < 8; ++nf) {
    int oc = wn * 128 + nf * 16 + l15;
    float sc = bn_s[oc] / sqrtf(bn_v[oc] + 1e-5f);
    float sh = (conv_b[oc] - bn_m[oc]) * sc + bn_b[oc];
    #pragma unroll
    for (int mf = 0; mf < 4; ++mf) {
      int hr = h0 + wm * 4 + mf;
      int w  = w0 + l4 * 4;
      float4 o;
      o.x = fmaxf(acc[mf][nf][0] * sc + sh, 0.f);
      o.y = fmaxf(acc[mf][nf][1] * sc + sh, 0.f);
      o.z = fmaxf(acc[mf][nf][2] * sc + sh, 0.f);
      o.w = fmaxf(acc[mf][nf][3] * sc + sh, 0.f);
      *(float4*)&yb[(size_t)oc * HW + hr * WWi + w] = o;
    }
  }
}

// ============ 1x1 stages: 3-way split MFMA, static acc, B direct from L2 (r14 proven) ============
// MODE 0: z1 = relu(bn2(pa@y + pa_b))        p0..p3 = bn2 s,b,m,v
// MODE 1: _c = l2n(ln(l2n(pb@z1 + pb_b)))    p0,p1 = fn_g,fn_b
template <int MODE>
__global__ __launch_bounds__(256, 2) void k_mlp_mfma(float* __restrict__ buf,
                                                     const short* __restrict__ pk_h,
                                                     const short* __restrict__ pk_m,
                                                     const short* __restrict__ pk_l,
                                                     const float* __restrict__ bias,
                                                     const float* __restrict__ p0,
                                                     const float* __restrict__ p1,
                                                     const float* __restrict__ p2,
                                                     const float* __restrict__ p3) {
  int bid = blockIdx.x;
  int b = bid >> 8, hw0 = (bid & 255) * 128;
  int tid = threadIdx.x;
  int lane = tid & 63, wv = tid >> 6;
  int wm = wv & 1, wn = wv >> 1;
  int l15 = lane & 15, l4 = lane >> 4;

  __shared__ short xt_h[128 * 36];
  __shared__ short xt_m[128 * 36];
  __shared__ short xt_l[128 * 36];
  __shared__ float redS[2][2][128];

  f32x4 acc[4][8];
  #pragma unroll
  for (int i = 0; i < 4; i++)
    #pragma unroll
    for (int j = 0; j < 8; j++) acc[i][j] = (f32x4){0.f, 0.f, 0.f, 0.f};

  const float* src = buf + (size_t)b * CHW + hw0;
  int boff = (wn * 128 + l15) * 36 + l4 * 8;

  #pragma unroll 1
  for (int icb = 0; icb < 8; ++icb) {
    int ic0 = icb << 5;
    #pragma unroll 4
    for (int idx = tid; idx < 2048; idx += 256) {
      int px = idx & 127, ip = idx >> 7;
      const float* p = src + (size_t)(ic0 + 2 * ip) * HW + px;
      float v0 = p[0], v1 = p[HW];
      unsigned hp, mp, lp;
      split3pack2(v0, v1, hp, mp, lp);
      int off = px * 36 + 2 * ip;
      *(unsigned*)&xt_h[off] = hp;
      *(unsigned*)&xt_m[off] = mp;
      *(unsigned*)&xt_l[off] = lp;
    }
    __syncthreads();
    const short* bh_base = pk_h + (size_t)icb * 256 * 36 + boff;
    const short* bm_base = pk_m + (size_t)icb * 256 * 36 + boff;
    const short* bl_base = pk_l + (size_t)icb * 256 * 36 + boff;
    bf16x8 ah[4], am[4], al[4];
    #pragma unroll
    for (int mf = 0; mf < 4; ++mf) {
      int off = (wm * 64 + mf * 16 + l15) * 36 + l4 * 8;
      ah[mf] = ldfrag(xt_h + off);
      am[mf] = ldfrag(xt_m + off);
      al[mf] = ldfrag(xt_l + off);
    }
    // term passes: hh, hm, mh, mm, hl, lh
    #pragma unroll
    for (int nf = 0; nf < 8; ++nf) {
      bf16x8 bh = ldfrag(bh_base + nf * 576);
      #pragma unroll
      for (int mf = 0; mf < 4; ++mf)
        acc[mf][nf] = __builtin_amdgcn_mfma_f32_16x16x32_bf16(ah[mf], bh, acc[mf][nf], 0, 0, 0);
    }
    #pragma unroll
    for (int nf = 0; nf < 8; ++nf) {
      bf16x8 bm = ldfrag(bm_base + nf * 576);
      #pragma unroll
      for (int mf = 0; mf < 4; ++mf)
        acc[mf][nf] = __builtin_amdgcn_mfma_f32_16x16x32_bf16(ah[mf], bm, acc[mf][nf], 0, 0, 0);
    }
    #pragma unroll
    for (int nf = 0; nf < 8; ++nf) {
      bf16x8 bh = ldfrag(bh_base + nf * 576);
      #pragma unroll
      for (int mf = 0; mf < 4; ++mf)
        acc[mf][nf] = __builtin_amdgcn_mfma_f32_16x16x32_bf16(am[mf], bh, acc[mf][nf], 0, 0, 0);
    }
    #pragma unroll
    for (int nf = 0; nf < 8; ++nf) {
      bf16x8 bm = ldfrag(bm_base + nf * 576);
      #pragma unroll
      for (int mf = 0; mf < 4; ++mf)
        acc[mf][nf] = __builtin_amdgcn_mfma_f32_16x16x32_bf16(am[mf], bm, acc[mf][nf], 0, 0, 0);
    }
    #pragma unroll
    for (int nf = 0; nf < 8; ++nf) {
      bf16x8 bl = ldfrag(bl_base + nf * 576);
      #pragma unroll
      for (int mf = 0; mf < 4; ++mf)
        acc[mf][nf] = __builtin_amdgcn_mfma_f32_16x16x32_bf16(ah[mf], bl, acc[mf][nf], 0, 0, 0);
    }
    #pragma unroll
    for (int nf = 0; nf < 8; ++nf) {
      bf16x8 bh = ldfrag(bh_base + nf * 576);
      #pragma unroll
      for (int mf = 0; mf < 4; ++mf)
        acc[mf][nf] = __builtin_amdgcn_mfma_f32_16x16x32_bf16(al[mf], bh, acc[mf][nf], 0, 0, 0);
    }
    __syncthreads();
  }

  float* dst = buf + (size_t)b * CHW + hw0;

  if (MODE == 0) {
    #pragma unroll
    for (int nf = 0; nf < 8; ++nf) {
      int oc = wn * 128 + nf * 16 + l15;
      float sc = p0[oc] / sqrtf(p3[oc] + 1e-5f);
      float sh = (bias[oc] - p2[oc]) * sc + p1[oc];
      #pragma unroll
      for (int mf = 0; mf < 4; ++mf) {
        float4 o;
        o.x = fmaxf(acc[mf][nf][0] * sc + sh, 0.f);
        o.y = fmaxf(acc[mf][nf][1] * sc + sh, 0.f);
        o.z = fmaxf(acc[mf][nf][2] * sc + sh, 0.f);
        o.w = fmaxf(acc[mf][nf][3] * sc + sh, 0.f);
        *(float4*)&dst[(size_t)oc * HW + wm * 64 + mf * 16 + l4 * 4] = o;
      }
    }
  } else {
    float bzv[8], gv[8], btv[8];
    #pragma unroll
    for (int nf = 0; nf < 8; ++nf) {
      int oc = wn * 128 + nf * 16 + l15;
      bzv[nf] = bias[oc];
      gv[nf] = p0[oc];
      btv[nf] = p1[oc];
    }
    float s1[4][4], s2[4][4];
    #pragma unroll
    for (int mf = 0; mf < 4; ++mf)
      #pragma unroll
      for (int rg = 0; rg < 4; ++rg) { s1[mf][rg] = 0.f; s2[mf][rg] = 0.f; }
    #pragma unroll
    for (int nf = 0; nf < 8; ++nf)
      #pragma unroll
      for (int mf = 0; mf < 4; ++mf)
        #pragma unroll
        for (int rg = 0; rg < 4; ++rg) {
          float z = acc[mf][nf][rg] + bzv[nf];
          acc[mf][nf][rg] = z;
          s1[mf][rg] += z;
          s2[mf][rg] += z * z;
        }
    #pragma unroll
    for (int mf = 0; mf < 4; ++mf)
      #pragma unroll
      for (int rg = 0; rg < 4; ++rg) {
        #pragma unroll
        for (int m = 1; m < 16; m <<= 1) {
          s1[mf][rg] += __shfl_xor(s1[mf][rg], m, 64);
          s2[mf][rg] += __shfl_xor(s2[mf][rg], m, 64);
        }
      }
    if (l15 == 0) {
      #pragma unroll
      for (int mf = 0; mf < 4; ++mf)
        #pragma unroll
        for (int rg = 0; rg < 4; ++rg) {
          int pxl = wm * 64 + mf * 16 + l4 * 4 + rg;
          redS[0][wn][pxl] = s1[mf][rg];
          redS[1][wn][pxl] = s2[mf][rg];
        }
    }
    __syncthreads();
    float s3[4][4];
    #pragma unroll
    for (int mf = 0; mf < 4; ++mf)
      #pragma unroll
      for (int rg = 0; rg < 4; ++rg) {
        int pxl = wm * 64 + mf * 16 + l4 * 4 + rg;
        float S1 = redS[0][0][pxl] + redS[0][1][pxl];
        float S2 = redS[1][0][pxl] + redS[1][1][pxl];
        float iv = 1.f / fmaxf(sqrtf(S2), 1e-12f);
        float mu = S1 * iv * (1.f / 256.f);
        float eu2 = S2 * iv * iv * (1.f / 256.f);
        float var = fmaxf(eu2 - mu * mu, 0.f);
        float rq = 1.f / sqrtf(var + 1e-5f);
        float s3loc = 0.f;
        #pragma unroll
        for (int nf = 0; nf < 8; ++nf) {
          float v = (acc[mf][nf][rg] * iv - mu) * rq * gv[nf] + btv[nf];
          acc[mf][nf][rg] = v;
          s3loc += v * v;
        }
        s3[mf][rg] = s3loc;
      }
    #pragma unroll
    for (int mf = 0; mf < 4; ++mf)
      #pragma unroll
      for (int rg = 0; rg < 4; ++rg) {
        #pragma unroll
        for (int m = 1; m < 16; m <<= 1)
          s3[mf][rg] += __shfl_xor(s3[mf][rg], m, 64);
      }
    __syncthreads();
    if (l15 == 0) {
      #pragma unroll
      for (int mf = 0; mf < 4; ++mf)
        #pragma unroll
        for (int rg = 0; rg < 4; ++rg) {
          int pxl = wm * 64 + mf * 16 + l4 * 4 + rg;
          redS[0][wn][pxl] = s3[mf][rg];
        }
    }
    __syncthreads();
    float cinv[4][4];
    #pragma unroll
    for (int mf = 0; mf < 4; ++mf)
      #pragma unroll
      for (int rg = 0; rg < 4; ++rg) {
        int pxl = wm * 64 + mf * 16 + l4 * 4 + rg;
        cinv[mf][rg] = 1.f / fmaxf(sqrtf(redS[0][0][pxl] + redS[0][1][pxl]), 1e-12f);
      }
    #pragma unroll
    for (int nf = 0; nf < 8; ++nf) {
      int oc = wn * 128 + nf * 16 + l15;
      #pragma unroll
      for (int mf = 0; mf < 4; ++mf) {
        float4 o;
        o.x = acc[mf][nf][0] * cinv[mf][0];
        o.y = acc[mf][nf][1] * cinv[mf][1];
        o.z = acc[mf][nf][2] * cinv[mf][2];
        o.w = acc[mf][nf][3] * cinv[mf][3];
        *(float4*)&dst[(size_t)oc * HW + wm * 64 + mf * 16 + l4 * 4] = o;
      }
    }
  }
}

// ============ masks GEMM: 64px x 192r, 3-way split MFMA, B direct from L2 (r14 proven) ============
__global__ __launch_bounds__(256, 2) void k_masks_mfma(const float* __restrict__ cbuf,
                                                       const short* __restrict__ pnk_h,
                                                       const short* __restrict__ pnk_m,
                                                       const short* __restrict__ pnk_l,
                                                       float* __restrict__ logits) {
  int bid = blockIdx.x;
  int b = bid >> 9, hw0 = (bid & 511) * 64;
  int tid = threadIdx.x;
  int lane = tid & 63, wn = tid >> 6;
  int l15 = lane & 15, l4 = lane >> 4;

  __shared__ short xt_h[64 * 36];
  __shared__ short xt_m[64 * 36];
  __shared__ short xt_l[64 * 36];

  f32x4 acc[4][3];
  #pragma unroll
  for (int i = 0; i < 4; i++)
    #pragma unroll
    for (int j = 0; j < 3; j++) acc[i][j] = (f32x4){0.f, 0.f, 0.f, 0.f};

  const float* src = cbuf + (size_t)b * CHW + hw0;
  int boff = (wn * 48 + l15) * 36 + l4 * 8;

  #pragma unroll 1
  for (int icb = 0; icb < 8; ++icb) {
    int ic0 = icb << 5;
    #pragma unroll 4
    for (int idx = tid; idx < 1024; idx += 256) {
      int px = idx & 63, ip = idx >> 6;
      const float* p = src + (size_t)(ic0 + 2 * ip) * HW + px;
      float v0 = p[0], v1 = p[HW];
      unsigned hp, mp, lp;
      split3pack2(v0, v1, hp, mp, lp);
      int off = px * 36 + 2 * ip;
      *(unsigned*)&xt_h[off] = hp;
      *(unsigned*)&xt_m[off] = mp;
      *(unsigned*)&xt_l[off] = lp;
    }
    __syncthreads();
    const short* bh_base = pnk_h + (size_t)icb * 192 * 36 + boff;
    const short* bm_base = pnk_m + (size_t)icb * 192 * 36 + boff;
    const short* bl_base = pnk_l + (size_t)icb * 192 * 36 + boff;
    bf16x8 ah[4], am[4], al[4];
    #pragma unroll
    for (int mf = 0; mf < 4; ++mf) {
      int off = (mf * 16 + l15) * 36 + l4 * 8;
      ah[mf] = ldfrag(xt_h + off);
      am[mf] = ldfrag(xt_m + off);
      al[mf] = ldfrag(xt_l + off);
    }
    #pragma unroll
    for (int nf = 0; nf < 3; ++nf) {
      bf16x8 bh = ldfrag(bh_base + nf * 576);
      #pragma unroll
      for (int mf = 0; mf < 4; ++mf)
        acc[mf][nf] = __builtin_amdgcn_mfma_f32_16x16x32_bf16(ah[mf], bh, acc[mf][nf], 0, 0, 0);
    }
    #pragma unroll
    for (int nf = 0; nf < 3; ++nf) {
      bf16x8 bm = ldfrag(bm_base + nf * 576);
      #pragma unroll
      for (int mf = 0; mf < 4; ++mf)
        acc[mf][nf] = __builtin_amdgcn_mfma_f32_16x16x32_bf16(ah[mf], bm, acc[mf][nf], 0, 0, 0);
    }
    #pragma unroll
    for (int nf = 0; nf < 3; ++nf) {
      bf16x8 bh = ldfrag(bh_base + nf * 576);
      #pragma unroll
      for (int mf = 0; mf < 4; ++mf)
        acc[mf][nf] = __builtin_amdgcn_mfma_f32_16x16x32_bf16(am[mf], bh, acc[mf][nf], 0, 0, 0);
    }
    #pragma unroll
    for (int nf = 0; nf < 3; ++nf) {
      bf16x8 bm = ldfrag(bm_base + nf * 576);
      #pragma unroll
      for (int mf = 0; mf < 4; ++mf)
        acc[mf][nf] = __builtin_amdgcn_mfma_f32_16x16x32_bf16(am[mf], bm, acc[mf][nf], 0, 0, 0);
    }
    #pragma unroll
    for (int nf = 0; nf < 3; ++nf) {
      bf16x8 bl = ldfrag(bl_base + nf * 576);
      #pragma unroll
      for (int mf = 0; mf < 4; ++mf)
        acc[mf][nf] = __builtin_amdgcn_mfma_f32_16x16x32_bf16(ah[mf], bl, acc[mf][nf], 0, 0, 0);
    }
    #pragma unroll
    for (int nf = 0; nf < 3; ++nf) {
      bf16x8 bh = ldfrag(bh_base + nf * 576);
      #pragma unroll
      for (int mf = 0; mf < 4; ++mf)
        acc[mf][nf] = __builtin_amdgcn_mfma_f32_16x16x32_bf16(al[mf], bh, acc[mf][nf], 0, 0, 0);
    }
    __syncthreads();
  }
  size_t n0 = (size_t)b * HW + hw0;
  #pragma unroll
  for (int nf = 0; nf < 3; ++nf) {
    int r = wn * 48 + nf * 16 + l15;
    if (r < RR) {
      #pragma unroll
      for (int mf = 0; mf < 4; ++mf) {
        int px = mf * 16 + l4 * 4;
        #pragma unroll
        for (int rg = 0; rg < 4; ++rg)
          logits[(n0 + px + rg) * RR + r] = acc[mf][nf][rg];
      }
    }
  }
}

// ============ out_seg = LN_k(max_j masks) + pred/correct ============
__global__ __launch_bounds__(256) void k_out(const float* __restrict__ logits,
                                             const int* __restrict__ gt,
                                             const float* __restrict__ mn_g,
                                             const float* __restrict__ mn_b,
                                             float* __restrict__ out_seg,
                                             int* __restrict__ corr) {
  __shared__ float lds[64][193];
  int n0 = blockIdx.x * 64;
  int tid = threadIdx.x;
  for (int idx = tid; idx < 64 * RR; idx += 256) {
    int rr = idx / RR, cc = idx - rr * RR;
    lds[rr][cc] = logits[(size_t)n0 * RR + idx];
  }
  __syncthreads();
  if (tid < 64) {
    int n = n0 + tid;
    float mx[KK];
    float S1 = 0.f, S2 = 0.f;
    #pragma unroll
    for (int k = 0; k < KK; k++) {
      float m_ = lds[tid][k * 10];
      #pragma unroll
      for (int j = 1; j < 10; j++) m_ = fmaxf(m_, lds[tid][k * 10 + j]);
      mx[k] = m_;
      S1 += m_;
      S2 += m_ * m_;
    }
    float mu = S1 * (1.f / 19.f);
    float var = fmaxf(S2 * (1.f / 19.f) - mu * mu, 0.f);
    float inv = 1.f / sqrtf(var + 1e-5f);
    int b = n >> 15, hw = n & 32767;
    float best = -3.4e38f;
    int pred = 0;
    #pragma unroll
    for (int k = 0; k < KK; k++) {
      float o = (mx[k] - mu) * inv * mn_g[k] + mn_b[k];
      out_seg[(size_t)b * 622592 + (size_t)k * 32768 + hw] = o;
      if (o > best) { best = o; pred = k; }
    }
    corr[n] = (gt[n] == pred) ? 1 : 0;
  }
}

// ============ sinkhorn reduction pass: T[k*10+j] += E * b(aprev) ============
__global__ __launch_bounds__(256) void k_sink_sum(const float* __restrict__ logits,
                                                  const int* __restrict__ gt,
                                                  float* __restrict__ Tout,
                                                  const float* __restrict__ aprev) {
  __shared__ float tl[RP];
  int tid = threadIdx.x;
  if (tid < RP) tl[tid] = 0.f;
  __syncthreads();
  int n = blockIdx.x * 256 + tid;
  int k = gt[n];
  const float* lp = logits + (size_t)n * RR + k * 10;
  float e[10];
  #pragma unroll
  for (int j = 0; j < 10; j++) e[j] = expf(lp[j] * 20.0f);
  float bfac = 1.f;
  if (aprev != nullptr) {
    float den = 0.f;
    #pragma unroll
    for (int j = 0; j < 10; j++) den += e[j] * aprev[k * 10 + j];
    bfac = 1.f / fmaxf(den, 1e-30f);
  }
  #pragma unroll
  for (int j = 0; j < 10; j++) atomicAdd(&tl[k * 10 + j], e[j] * bfac);
  __syncthreads();
  if (tid < RR) atomicAdd(&Tout[tid], tl[tid]);
}

__global__ __launch_bounds__(256) void k_calc_a(const float* __restrict__ T,
                                                float* __restrict__ a) {
  int t = threadIdx.x;
  if (t < RR) a[t] = 1.f / (10.f * fmaxf(T[t], 1e-12f));
  else if (t < RP) a[t] = 0.f;
}

// ============ final sinkhorn pass: proto_target, gumbel-hard key, n_cnt ============
__global__ __launch_bounds__(256) void k_final(const float* __restrict__ logits,
                                               const int* __restrict__ gt,
                                               const float* __restrict__ a3,
                                               const float* __restrict__ gu,
                                               const int* __restrict__ corr,
                                               float* __restrict__ tgt,
                                               int* __restrict__ key,
                                               int* __restrict__ ncnt) {
  int n = blockIdx.x * 256 + threadIdx.x;
  int k = gt[n];
  const float* lp = logits + (size_t)n * RR + k * 10;
  float w[10];
  float den = 0.f, bestw = -1.f;
  int idx = 0;
  #pragma unroll
  for (int j = 0; j < 10; j++) {
    w[j] = expf(lp[j] * 20.0f) * a3[k * 10 + j];
    den += w[j];
    if (w[j] > bestw) { bestw = w[j]; idx = j; }
  }
  tgt[n] = (float)(idx + 10 * k);
  float dinv = 1.f / fmaxf(den, 1e-30f);
  const float* gp = gu + ((size_t)k * NN + n) * 10;
  float bestq = -3.4e38f;
  int jh = 0;
  #pragma unroll
  for (int j = 0; j < 10; j++) {
    float g = -logf(-logf(gp[j] + 1e-20f) + 1e-20f);
    float q = w[j] * dinv + g;
    if (q > bestq) { bestq = q; jh = j; }
  }
  int kv = -1;
  if (corr[n]) {
    kv = k * 10 + jh;
    atomicAdd(&ncnt[kv], 1);
  }
  key[n] = kv;
}

// ============ f[k,j,:] += _c[n,:] over counted samples ============
__global__ __launch_bounds__(256) void k_accum_f(const int* __restrict__ key,
                                                 const float* __restrict__ cbuf,
                                                 float* __restrict__ f) {
  __shared__ int ks[64];
  int n0 = blockIdx.x * 64;
  int tid = threadIdx.x;
  if (tid < 64) ks[tid] = key[n0 + tid];
  __syncthreads();
  for (int s = 0; s < 64; s++) {
    int kv = ks[s];
    if (kv >= 0) {
      int n = n0 + s;
      int b = n >> 15, hw = n & 32767;
      atomicAdd(&f[kv * 256 + tid], cbuf[(size_t)b * CHW + (size_t)tid * HW + hw]);
    }
  }
}

// ============ prototype EMA update + renormalize ============
__global__ __launch_bounds__(256) void k_update(const float* __restrict__ Pn,
                                                const float* __restrict__ f,
                                                const int* __restrict__ ncnt,
                                                float* __restrict__ outP) {
  int r = blockIdx.x, d = threadIdx.x;
  int k = r / 10;
  __shared__ float red[256];
  __shared__ int hasS;
  if (d == 0) {
    int s = 0;
    for (int j = 0; j < 10; j++) s += ncnt[k * 10 + j];
    hasS = s;
  }
  __syncthreads();
  bool upd = (ncnt[r] != 0) && (hasS > 0);
  float fv = f[r * 256 + d];
  red[d] = fv * fv;
  __syncthreads();
  #pragma unroll
  for (int s = 128; s > 0; s >>= 1) {
    if (d < s) red[d] += red[d + s];
    __syncthreads();
  }
  float fn2 = red[0];
  __syncthreads();
  float fl = fv / fmaxf(sqrtf(fn2), 1e-12f);
  float p = Pn[r * 256 + d];
  float nv = upd ? (0.999f * p + 0.001f * fl) : p;
  red[d] = nv * nv;
  __syncthreads();
  #pragma unroll
  for (int s = 128; s > 0; s >>= 1) {
    if (d < s) red[d] += red[d + s];
    __syncthreads();
  }
  outP[r * 256 + d] = nv / fmaxf(sqrtf(red[0]), 1e-12f);
}

// ============ launch ============
extern "C" void kernel_launch(void* const* d_in, const int* in_sizes, int n_in,
                              void* d_out, int out_size, void* d_ws, size_t ws_size,
                              hipStream_t stream) {
  const float* x      = (const float*)d_in[0];
  const int*   gt     = (const int*)  d_in[1];
  const float* gu     = (const float*)d_in[2];
  const float* conv_w = (const float*)d_in[3];
  const float* conv_b = (const float*)d_in[4];
  const float* bn1_s  = (const float*)d_in[5];
  const float* bn1_b  = (const float*)d_in[6];
  const float* bn1_m  = (const float*)d_in[7];
  const float* bn1_v  = (const float*)d_in[8];
  const float* pa_w   = (const float*)d_in[9];
  const float* pa_b   = (const float*)d_in[10];
  const float* bn2_s  = (const float*)d_in[11];
  const float* bn2_b  = (const float*)d_in[12];
  const float* bn2_m  = (const float*)d_in[13];
  const float* bn2_v  = (const float*)d_in[14];
  const float* pb_w   = (const float*)d_in[15];
  const float* pb_b   = (const float*)d_in[16];
  const float* fn_g   = (const float*)d_in[17];
  const float* fn_b   = (const float*)d_in[18];
  const float* mn_g   = (const float*)d_in[19];
  const float* mn_b   = (const float*)d_in[20];
  const float* protos = (const float*)d_in[21];

  float* ws  = (float*)d_ws;
  float* out = (float*)d_out;

  float* buf   = ws + WS_BUF;
  short* wpk_h = (short*)(ws + WS_WPK);
  short* wpk_l = wpk_h + 9 * 8 * 256 * 36;
  short* ppa_h = (short*)(ws + WS_PPA);
  short* ppa_m = ppa_h + 8 * 256 * 36;
  short* ppa_l = ppa_h + 2 * 8 * 256 * 36;
  short* ppb_h = (short*)(ws + WS_PPB);
  short* ppb_m = ppb_h + 8 * 256 * 36;
  short* ppb_l = ppb_h + 2 * 8 * 256 * 36;
  float* Pn    = ws + WS_PN;
  short* pnk_h = (short*)(ws + WS_PNK);
  short* pnk_m = pnk_h + 8 * 192 * 36;
  short* pnk_l = pnk_h + 2 * 8 * 192 * 36;
  float* Tarr  = ws + WS_T;
  float* farr  = ws + WS_F;
  float* aarr  = ws + WS_A;
  int*   ncnt  = (int*)(ws + WS_NCNT);
  int*   corr  = (int*)(ws + WS_CORR);
  int*   key   = (int*)(ws + WS_KEY);

  float* logits = out + O_LOG;

  // zero T[576] + f[48640] + a[576] + ncnt[192]  (contiguous region)
  hipMemsetAsync(ws + WS_T, 0, (size_t)(576 + 48640 + 576 + 192) * 4, stream);

  k_prep_protos<<<RP, 256, 0, stream>>>(protos, Pn, pnk_h, pnk_m, pnk_l);
  k_prep_wsplit<<<72, 256, 0, stream>>>(conv_w, wpk_h, wpk_l);
  k_prep_packs<<<16, 256, 0, stream>>>(pa_w, pb_w, ppa_h, ppa_m, ppa_l,
                                       ppb_h, ppb_m, ppb_l);
  k_conv_mfma<<<1024, 256, 0, stream>>>(x, wpk_h, wpk_l, conv_b,
                                        bn1_s, bn1_b, bn1_m, bn1_v, buf);
  k_mlp_mfma<0><<<1024, 256, 0, stream>>>(buf, ppa_h, ppa_m, ppa_l, pa_b,
                                          bn2_s, bn2_b, bn2_m, bn2_v);
  k_mlp_mfma<1><<<1024, 256, 0, stream>>>(buf, ppb_h, ppb_m, ppb_l, pb_b,
                                          fn_g, fn_b, nullptr, nullptr);
  k_masks_mfma<<<2048, 256, 0, stream>>>(buf, pnk_h, pnk_m, pnk_l, logits);
  k_out<<<2048, 256, 0, stream>>>(logits, gt, mn_g, mn_b, out, corr);
  k_sink_sum<<<512, 256, 0, stream>>>(logits, gt, Tarr + 0,   nullptr);
  k_calc_a<<<1, 256, 0, stream>>>(Tarr + 0,   aarr + 0);
  k_sink_sum<<<512, 256, 0, stream>>>(logits, gt, Tarr + 192, aarr + 0);
  k_calc_a<<<1, 256, 0, stream>>>(Tarr + 192, aarr + 192);
  k_sink_sum<<<512, 256, 0, stream>>>(logits, gt, Tarr + 384, aarr + 192);
  k_calc_a<<<1, 256, 0, stream>>>(Tarr + 384, aarr + 384);
  k_final<<<512, 256, 0, stream>>>(logits, gt, aarr + 384, gu, corr, out + O_TGT, key, ncnt);
  k_accum_f<<<2048, 256, 0, stream>>>(key, buf, farr);
  k_update<<<190, 256, 0, stream>>>(Pn, farr, ncnt, out + O_PROTO);

  (void)in_sizes; (void)n_in; (void)out_size; (void)ws_size;
}

// Round 16
// 886.565 us; speedup vs baseline: 1.0810x; 1.0810x over previous
//
#include <hip/hip_runtime.h>
#include <cstddef>
#include <cstdint>

// ---------------- problem constants ----------------
#define BB   4
#define CC   256
#define HHh  128
#define WWi  256
#define HW   32768      // H*W
#define CHW  8388608    // C*H*W
#define NN   131072     // B*H*W
#define KK   19
#define MMp  10
#define RR   190        // K*M
#define RP   192

// ---------------- output offsets (floats) ----------------
#define O_LOG   2490368     // out_seg size = 4*19*128*256
#define O_TGT   27394048
#define O_PROTO 27525120

// ---------------- ws offsets (floats) ----------------
#define WS_BUF   0           // 33,554,432 : y -> z1 -> _c (in-place, [b][c][h][w])
#define WS_WPK   33554432    // 663,552 : conv 2-way split (2 x 663552 shorts)
#define WS_PPA   34217984    // 110,592 : pa 3-way split (3 x 73728 shorts) [icb][oc][36]
#define WS_PPB   34328576    // 110,592 : pb 3-way split
#define WS_PN    34439168    // 48,640  : normalized protos [190][256] f32
#define WS_PNK   34487808    // 82,944  : proto 3-way split (3 x 55296 shorts) [icb][192][36]
#define WS_T     34570752    // 3*192 sinkhorn sums
#define WS_F     34571328    // 48,640 : f accumulator
#define WS_A     34619968    // 3*192 sinkhorn row scales
#define WS_NCNT  34620544    // 192 int
#define WS_CORR  34620736    // 131,072 int
#define WS_KEY   34751808    // 131,072 int
// end = 34,882,880 floats = 139.5 MB

typedef __attribute__((ext_vector_type(8))) short bf16x8;
typedef __attribute__((ext_vector_type(4))) short s16x4;
typedef __attribute__((ext_vector_type(4))) float f32x4;

__device__ __forceinline__ void split2pack(float v0, float v1, unsigned& hp, unsigned& lp) {
  unsigned u0 = __float_as_uint(v0), u1 = __float_as_uint(v1);
  unsigned h0 = u0 & 0xffff0000u, h1 = u1 & 0xffff0000u;
  float r0 = v0 - __uint_as_float(h0);
  float r1 = v1 - __uint_as_float(h1);
  hp = (h0 >> 16) | h1;
  lp = (__float_as_uint(r0) >> 16) | (__float_as_uint(r1) & 0xffff0000u);
}

__device__ __forceinline__ void split1(float v, short& h, short& l) {
  unsigned u = __float_as_uint(v);
  unsigned hm = u & 0xffff0000u;
  float r = v - __uint_as_float(hm);
  h = (short)(hm >> 16);
  l = (short)(__float_as_uint(r) >> 16);
}

__device__ __forceinline__ void split3s(float v, short& h, short& m, short& l) {
  unsigned u = __float_as_uint(v);
  unsigned hm = u & 0xffff0000u;
  float r1 = v - __uint_as_float(hm);
  unsigned mm = __float_as_uint(r1) & 0xffff0000u;
  float r2 = r1 - __uint_as_float(mm);
  h = (short)(hm >> 16);
  m = (short)(mm >> 16);
  l = (short)(__float_as_uint(r2) >> 16);
}

__device__ __forceinline__ void split3pack2(float v0, float v1,
                                            unsigned& hp, unsigned& mp, unsigned& lp) {
  unsigned u0 = __float_as_uint(v0), u1 = __float_as_uint(v1);
  unsigned h0 = u0 & 0xffff0000u, h1 = u1 & 0xffff0000u;
  float r0 = v0 - __uint_as_float(h0);
  float r1 = v1 - __uint_as_float(h1);
  unsigned m0 = __float_as_uint(r0) & 0xffff0000u, m1 = __float_as_uint(r1) & 0xffff0000u;
  float s0 = r0 - __uint_as_float(m0);
  float s1 = r1 - __uint_as_float(m1);
  hp = (h0 >> 16) | h1;
  mp = (m0 >> 16) | m1;
  lp = (__float_as_uint(s0) >> 16) | (__float_as_uint(s1) & 0xffff0000u);
}

__device__ __forceinline__ bf16x8 ldfrag(const short* p) {
  union { bf16x8 v; s16x4 q[2]; } u;
  u.q[0] = *(const s16x4*)p;
  u.q[1] = *(const s16x4*)(p + 4);
  return u.v;
}

// ============ prototype normalize + 3-way split-pack ============
__global__ __launch_bounds__(256) void k_prep_protos(const float* __restrict__ protos,
                                                     float* __restrict__ Pn,
                                                     short* __restrict__ pnk_h,
                                                     short* __restrict__ pnk_m,
                                                     short* __restrict__ pnk_l) {
  int r = blockIdx.x, d = threadIdx.x;
  int icb = d >> 5, i = d & 31;
  int base = (icb * 192 + r) * 36;
  if (r >= RR) {       // zero pad rows 190,191
    pnk_h[base + i] = 0; pnk_m[base + i] = 0; pnk_l[base + i] = 0;
    if (i < 4) { pnk_h[base + 32 + i] = 0; pnk_m[base + 32 + i] = 0; pnk_l[base + 32 + i] = 0; }
    return;
  }
  float v = protos[r * 256 + d];
  __shared__ float red[256];
  red[d] = v * v;
  __syncthreads();
  #pragma unroll
  for (int s = 128; s > 0; s >>= 1) {
    if (d < s) red[d] += red[d + s];
    __syncthreads();
  }
  float inv = 1.f / fmaxf(sqrtf(red[0]), 1e-12f);
  float pv = v * inv;
  Pn[r * 256 + d] = pv;
  short h, m, l;
  split3s(pv, h, m, l);
  pnk_h[base + i] = h; pnk_m[base + i] = m; pnk_l[base + i] = l;
  if (i < 4) { pnk_h[base + 32 + i] = 0; pnk_m[base + 32 + i] = 0; pnk_l[base + 32 + i] = 0; }
}

// ============ conv weight 2-way split-pack ============
__global__ __launch_bounds__(256) void k_prep_wsplit(const float* __restrict__ conv_w,
                                                     short* __restrict__ wpk_h,
                                                     short* __restrict__ wpk_l) {
  int blk = blockIdx.x;             // t9*8 + icb
  int t9 = blk >> 3, icb = blk & 7;
  int oc = threadIdx.x;
  short* dh = wpk_h + ((size_t)blk * 256 + oc) * 36;
  short* dl = wpk_l + ((size_t)blk * 256 + oc) * 36;
  #pragma unroll 4
  for (int i = 0; i < 32; i++) {
    float v = conv_w[((size_t)oc * 256 + icb * 32 + i) * 9 + t9];
    short h, l;
    split1(v, h, l);
    dh[i] = h; dl[i] = l;
  }
  #pragma unroll
  for (int i = 32; i < 36; i++) { dh[i] = 0; dl[i] = 0; }
}

// ============ 1x1 weight 3-way split-pack (pa, pb) ============
__global__ __launch_bounds__(256) void k_prep_packs(const float* __restrict__ pa_w,
                                                    const float* __restrict__ pb_w,
                                                    short* __restrict__ ppa_h,
                                                    short* __restrict__ ppa_m,
                                                    short* __restrict__ ppa_l,
                                                    short* __restrict__ ppb_h,
                                                    short* __restrict__ ppb_m,
                                                    short* __restrict__ ppb_l) {
  int blk = blockIdx.x;
  const float* W;
  short *dh, *dm, *dl;
  int icb;
  if (blk < 8) { icb = blk;     W = pa_w; dh = ppa_h; dm = ppa_m; dl = ppa_l; }
  else         { icb = blk - 8; W = pb_w; dh = ppb_h; dm = ppb_m; dl = ppb_l; }
  int oc = threadIdx.x;
  size_t base = ((size_t)icb * 256 + oc) * 36;
  dh += base; dm += base; dl += base;
  #pragma unroll 4
  for (int i = 0; i < 32; i++) {
    float v = W[(size_t)oc * 256 + icb * 32 + i];
    short h, m, l;
    split3s(v, h, m, l);
    dh[i] = h; dm[i] = m; dl[i] = l;
  }
  #pragma unroll
  for (int i = 32; i < 36; i++) { dh[i] = 0; dm[i] = 0; dl[i] = 0; }
}

// ============ conv3x3 + bias + bn1 + relu : r14 proven best (466us) ============
__global__ __launch_bounds__(256, 2) void k_conv_mfma(const float* __restrict__ x,
                                                      const short* __restrict__ wpk_h,
                                                      const short* __restrict__ wpk_l,
                                                      const float* __restrict__ conv_b,
                                                      const float* __restrict__ bn_s,
                                                      const float* __restrict__ bn_b,
                                                      const float* __restrict__ bn_m,
                                                      const float* __restrict__ bn_v,
                                                      float* __restrict__ y) {
  int bid = blockIdx.x;
  int tw = bid & 15, th = (bid >> 4) & 15, b = bid >> 8;
  int h0 = th * 8, w0 = tw * 16;
  int tid = threadIdx.x;
  int lane = tid & 63, wv = tid >> 6;
  int wm = wv & 1, wn = wv >> 1;
  int l15 = lane & 15, l4 = lane >> 4;

  __shared__ short xt_h[2][10 * 18 * 36];
  __shared__ short xt_l[2][10 * 18 * 36];

  f32x4 acc[4][8];
  #pragma unroll
  for (int i = 0; i < 4; i++)
    #pragma unroll
    for (int j = 0; j < 8; j++) acc[i][j] = (f32x4){0.f, 0.f, 0.f, 0.f};

  const float* xb = x + (size_t)b * CHW;
  int boff = (wn * 128 + l15) * 36 + l4 * 8;

  auto stageA = [&](int icb, int p) {
    int ic0 = icb << 5;
    short* dh = xt_h[p];
    short* dl = xt_l[p];
    #pragma unroll 4
    for (int idx = tid; idx < 2880; idx += 256) {
      int ww = idx % 18;
      int t  = idx / 18;
      int r  = t % 10;
      int ip = t / 10;
      int hh = h0 - 1 + r, wg = w0 - 1 + ww;
      float v0 = 0.f, v1 = 0.f;
      if ((unsigned)hh < 128u && (unsigned)wg < 256u) {
        const float* px = xb + (size_t)(ic0 + 2 * ip) * HW + hh * WWi + wg;
        v0 = px[0]; v1 = px[HW];
      }
      unsigned hp, lp;
      split2pack(v0, v1, hp, lp);
      int off = (r * 18 + ww) * 36 + 2 * ip;
      *(unsigned*)&dh[off] = hp;
      *(unsigned*)&dl[off] = lp;
    }
  };

  stageA(0, 0);
  __syncthreads();

  #pragma unroll 1
  for (int icb = 0; icb < 8; ++icb) {
    int cur = icb & 1;
    if (icb < 7) stageA(icb + 1, cur ^ 1);
    const short* xa_h = xt_h[cur];
    const short* xa_l = xt_l[cur];
    #pragma unroll 1
    for (int kh = 0; kh < 3; ++kh) {
      #pragma unroll 1
      for (int kw = 0; kw < 3; ++kw) {
        int t9 = kh * 3 + kw;
        const short* bh_base = wpk_h + ((size_t)(t9 * 8 + icb) * 256) * 36 + boff;
        const short* bl_base = wpk_l + ((size_t)(t9 * 8 + icb) * 256) * 36 + boff;
        bf16x8 ah[4], al[4];
        #pragma unroll
        for (int mf = 0; mf < 4; ++mf) {
          int off = ((wm * 4 + mf + kh) * 18 + l15 + kw) * 36 + l4 * 8;
          ah[mf] = ldfrag(xa_h + off);
          al[mf] = ldfrag(xa_l + off);
        }
        #pragma unroll
        for (int nf = 0; nf < 8; ++nf) {
          bf16x8 bh = ldfrag(bh_base + nf * 576);
          bf16x8 bl = ldfrag(bl_base + nf * 576);
          #pragma unroll
          for (int mf = 0; mf < 4; ++mf) {
            acc[mf][nf] = __builtin_amdgcn_mfma_f32_16x16x32_bf16(ah[mf], bh, acc[mf][nf], 0, 0, 0);
            acc[mf][nf] = __builtin_amdgcn_mfma_f32_16x16x32_bf16(ah[mf], bl, acc[mf][nf], 0, 0, 0);
            acc[mf][nf] = __builtin_amdgcn_mfma_f32_16x16x32_bf16(al[mf], bh, acc[mf][nf], 0, 0, 0);
          }
        }
      }
    }
    __syncthreads();
  }
  float* yb = y + (size_t)b * CHW;
  #pragma unroll
  for (int nf = 0; nf < 8; ++nf) {
    int oc = wn * 128 + nf * 16 + l15;
    float sc = bn_s[oc] / sqrtf(bn_v[oc] + 1e-5f);
    float sh = (conv_b[oc] - bn_m[oc]) * sc + bn_b[oc];
    #pragma unroll
    for (int mf = 0; mf < 4; ++mf) {
      int hr = h0 + wm * 4 + mf;
      int w  = w0 + l4 * 4;
      float4 o;
      o.x = fmaxf(acc[mf][nf][0] * sc + sh, 0.f);
      o.y = fmaxf(acc[mf][nf][1] * sc + sh, 0.f);
      o.z = fmaxf(acc[mf][nf][2] * sc + sh, 0.f);
      o.w = fmaxf(acc[mf][nf][3] * sc + sh, 0.f);
      *(float4*)&yb[(size_t)oc * HW + hr * WWi + w] = o;
    }
  }
}

// ============ 1x1 stages: 3-way split MFMA, static acc, B direct from L2 (r14 proven) ============
// MODE 0: z1 = relu(bn2(pa@y + pa_b))        p0..p3 = bn2 s,b,m,v
// MODE 1: _c = l2n(ln(l2n(pb@z1 + pb_b)))    p0,p1 = fn_g,fn_b
template <int MODE>
__global__ __launch_bounds__(256, 2) void k_mlp_mfma(float* __restrict__ buf,
                                                     const short* __restrict__ pk_h,
                                                     const short* __restrict__ pk_m,
                                                     const short* __restrict__ pk_l,
                                                     const float* __restrict__ bias,
                                                     const float* __restrict__ p0,
                                                     const float* __restrict__ p1,
                                                     const float* __restrict__ p2,
                                                     const float* __restrict__ p3) {
  int bid = blockIdx.x;
  int b = bid >> 8, hw0 = (bid & 255) * 128;
  int tid = threadIdx.x;
  int lane = tid & 63, wv = tid >> 6;
  int wm = wv & 1, wn = wv >> 1;
  int l15 = lane & 15, l4 = lane >> 4;

  __shared__ short xt_h[128 * 36];
  __shared__ short xt_m[128 * 36];
  __shared__ short xt_l[128 * 36];
  __shared__ float redS[2][2][128];

  f32x4 acc[4][8];
  #pragma unroll
  for (int i = 0; i < 4; i++)
    #pragma unroll
    for (int j = 0; j < 8; j++) acc[i][j] = (f32x4){0.f, 0.f, 0.f, 0.f};

  const float* src = buf + (size_t)b * CHW + hw0;
  int boff = (wn * 128 + l15) * 36 + l4 * 8;

  #pragma unroll 1
  for (int icb = 0; icb < 8; ++icb) {
    int ic0 = icb << 5;
    #pragma unroll 4
    for (int idx = tid; idx < 2048; idx += 256) {
      int px = idx & 127, ip = idx >> 7;
      const float* p = src + (size_t)(ic0 + 2 * ip) * HW + px;
      float v0 = p[0], v1 = p[HW];
      unsigned hp, mp, lp;
      split3pack2(v0, v1, hp, mp, lp);
      int off = px * 36 + 2 * ip;
      *(unsigned*)&xt_h[off] = hp;
      *(unsigned*)&xt_m[off] = mp;
      *(unsigned*)&xt_l[off] = lp;
    }
    __syncthreads();
    const short* bh_base = pk_h + (size_t)icb * 256 * 36 + boff;
    const short* bm_base = pk_m + (size_t)icb * 256 * 36 + boff;
    const short* bl_base = pk_l + (size_t)icb * 256 * 36 + boff;
    bf16x8 ah[4], am[4], al[4];
    #pragma unroll
    for (int mf = 0; mf < 4; ++mf) {
      int off = (wm * 64 + mf * 16 + l15) * 36 + l4 * 8;
      ah[mf] = ldfrag(xt_h + off);
      am[mf] = ldfrag(xt_m + off);
      al[mf] = ldfrag(xt_l + off);
    }
    // term passes: hh, hm, mh, mm, hl, lh
    #pragma unroll
    for (int nf = 0; nf < 8; ++nf) {
      bf16x8 bh = ldfrag(bh_base + nf * 576);
      #pragma unroll
      for (int mf = 0; mf < 4; ++mf)
        acc[mf][nf] = __builtin_amdgcn_mfma_f32_16x16x32_bf16(ah[mf], bh, acc[mf][nf], 0, 0, 0);
    }
    #pragma unroll
    for (int nf = 0; nf < 8; ++nf) {
      bf16x8 bm = ldfrag(bm_base + nf * 576);
      #pragma unroll
      for (int mf = 0; mf < 4; ++mf)
        acc[mf][nf] = __builtin_amdgcn_mfma_f32_16x16x32_bf16(ah[mf], bm, acc[mf][nf], 0, 0, 0);
    }
    #pragma unroll
    for (int nf = 0; nf < 8; ++nf) {
      bf16x8 bh = ldfrag(bh_base + nf * 576);
      #pragma unroll
      for (int mf = 0; mf < 4; ++mf)
        acc[mf][nf] = __builtin_amdgcn_mfma_f32_16x16x32_bf16(am[mf], bh, acc[mf][nf], 0, 0, 0);
    }
    #pragma unroll
    for (int nf = 0; nf < 8; ++nf) {
      bf16x8 bm = ldfrag(bm_base + nf * 576);
      #pragma unroll
      for (int mf = 0; mf < 4; ++mf)
        acc[mf][nf] = __builtin_amdgcn_mfma_f32_16x16x32_bf16(am[mf], bm, acc[mf][nf], 0, 0, 0);
    }
    #pragma unroll
    for (int nf = 0; nf < 8; ++nf) {
      bf16x8 bl = ldfrag(bl_base + nf * 576);
      #pragma unroll
      for (int mf = 0; mf < 4; ++mf)
        acc[mf][nf] = __builtin_amdgcn_mfma_f32_16x16x32_bf16(ah[mf], bl, acc[mf][nf], 0, 0, 0);
    }
    #pragma unroll
    for (int nf = 0; nf < 8; ++nf) {
      bf16x8 bh = ldfrag(bh_base + nf * 576);
      #pragma unroll
      for (int mf = 0; mf < 4; ++mf)
        acc[mf][nf] = __builtin_amdgcn_mfma_f32_16x16x32_bf16(al[mf], bh, acc[mf][nf], 0, 0, 0);
    }
    __syncthreads();
  }

  float* dst = buf + (size_t)b * CHW + hw0;

  if (MODE == 0) {
    #pragma unroll
    for (int nf = 0; nf < 8; ++nf) {
      int oc = wn * 128 + nf * 16 + l15;
      float sc = p0[oc] / sqrtf(p3[oc] + 1e-5f);
      float sh = (bias[oc] - p2[oc]) * sc + p1[oc];
      #pragma unroll
      for (int mf = 0; mf < 4; ++mf) {
        float4 o;
        o.x = fmaxf(acc[mf][nf][0] * sc + sh, 0.f);
        o.y = fmaxf(acc[mf][nf][1] * sc + sh, 0.f);
        o.z = fmaxf(acc[mf][nf][2] * sc + sh, 0.f);
        o.w = fmaxf(acc[mf][nf][3] * sc + sh, 0.f);
        *(float4*)&dst[(size_t)oc * HW + wm * 64 + mf * 16 + l4 * 4] = o;
      }
    }
  } else {
    float bzv[8], gv[8], btv[8];
    #pragma unroll
    for (int nf = 0; nf < 8; ++nf) {
      int oc = wn * 128 + nf * 16 + l15;
      bzv[nf] = bias[oc];
      gv[nf] = p0[oc];
      btv[nf] = p1[oc];
    }
    float s1[4][4], s2[4][4];
    #pragma unroll
    for (int mf = 0; mf < 4; ++mf)
      #pragma unroll
      for (int rg = 0; rg < 4; ++rg) { s1[mf][rg] = 0.f; s2[mf][rg] = 0.f; }
    #pragma unroll
    for (int nf = 0; nf < 8; ++nf)
      #pragma unroll
      for (int mf = 0; mf < 4; ++mf)
        #pragma unroll
        for (int rg = 0; rg < 4; ++rg) {
          float z = acc[mf][nf][rg] + bzv[nf];
          acc[mf][nf][rg] = z;
          s1[mf][rg] += z;
          s2[mf][rg] += z * z;
        }
    #pragma unroll
    for (int mf = 0; mf < 4; ++mf)
      #pragma unroll
      for (int rg = 0; rg < 4; ++rg) {
        #pragma unroll
        for (int m = 1; m < 16; m <<= 1) {
          s1[mf][rg] += __shfl_xor(s1[mf][rg], m, 64);
          s2[mf][rg] += __shfl_xor(s2[mf][rg], m, 64);
        }
      }
    if (l15 == 0) {
      #pragma unroll
      for (int mf = 0; mf < 4; ++mf)
        #pragma unroll
        for (int rg = 0; rg < 4; ++rg) {
          int pxl = wm * 64 + mf * 16 + l4 * 4 + rg;
          redS[0][wn][pxl] = s1[mf][rg];
          redS[1][wn][pxl] = s2[mf][rg];
        }
    }
    __syncthreads();
    float s3[4][4];
    #pragma unroll
    for (int mf = 0; mf < 4; ++mf)
      #pragma unroll
      for (int rg = 0; rg < 4; ++rg) {
        int pxl = wm * 64 + mf * 16 + l4 * 4 + rg;
        float S1 = redS[0][0][pxl] + redS[0][1][pxl];
        float S2 = redS[1][0][pxl] + redS[1][1][pxl];
        float iv = 1.f / fmaxf(sqrtf(S2), 1e-12f);
        float mu = S1 * iv * (1.f / 256.f);
        float eu2 = S2 * iv * iv * (1.f / 256.f);
        float var = fmaxf(eu2 - mu * mu, 0.f);
        float rq = 1.f / sqrtf(var + 1e-5f);
        float s3loc = 0.f;
        #pragma unroll
        for (int nf = 0; nf < 8; ++nf) {
          float v = (acc[mf][nf][rg] * iv - mu) * rq * gv[nf] + btv[nf];
          acc[mf][nf][rg] = v;
          s3loc += v * v;
        }
        s3[mf][rg] = s3loc;
      }
    #pragma unroll
    for (int mf = 0; mf < 4; ++mf)
      #pragma unroll
      for (int rg = 0; rg < 4; ++rg) {
        #pragma unroll
        for (int m = 1; m < 16; m <<= 1)
          s3[mf][rg] += __shfl_xor(s3[mf][rg], m, 64);
      }
    __syncthreads();
    if (l15 == 0) {
      #pragma unroll
      for (int mf = 0; mf < 4; ++mf)
        #pragma unroll
        for (int rg = 0; rg < 4; ++rg) {
          int pxl = wm * 64 + mf * 16 + l4 * 4 + rg;
          redS[0][wn][pxl] = s3[mf][rg];
        }
    }
    __syncthreads();
    float cinv[4][4];
    #pragma unroll
    for (int mf = 0; mf < 4; ++mf)
      #pragma unroll
      for (int rg = 0; rg < 4; ++rg) {
        int pxl = wm * 64 + mf * 16 + l4 * 4 + rg;
        cinv[mf][rg] = 1.f / fmaxf(sqrtf(redS[0][0][pxl] + redS[0][1][pxl]), 1e-12f);
      }
    #pragma unroll
    for (int nf = 0; nf < 8; ++nf) {
      int oc = wn * 128 + nf * 16 + l15;
      #pragma unroll
      for (int mf = 0; mf < 4; ++mf) {
        float4 o;
        o.x = acc[mf][nf][0] * cinv[mf][0];
        o.y = acc[mf][nf][1] * cinv[mf][1];
        o.z = acc[mf][nf][2] * cinv[mf][2];
        o.w = acc[mf][nf][3] * cinv[mf][3];
        *(float4*)&dst[(size_t)oc * HW + wm * 64 + mf * 16 + l4 * 4] = o;
      }
    }
  }
}

// ============ masks GEMM: 64px x 192r, 3-way split MFMA, B direct from L2 (r14 proven) ============
__global__ __launch_bounds__(256, 2) void k_masks_mfma(const float* __restrict__ cbuf,
                                                       const short* __restrict__ pnk_h,
                                                       const short* __restrict__ pnk_m,
                                                       const short* __restrict__ pnk_l,
                                                       float* __restrict__ logits) {
  int bid = blockIdx.x;
  int b = bid >> 9, hw0 = (bid & 511) * 64;
  int tid = threadIdx.x;
  int lane = tid & 63, wn = tid >> 6;
  int l15 = lane & 15, l4 = lane >> 4;

  __shared__ short xt_h[64 * 36];
  __shared__ short xt_m[64 * 36];
  __shared__ short xt_l[64 * 36];

  f32x4 acc[4][3];
  #pragma unroll
  for (int i = 0; i < 4; i++)
    #pragma unroll
    for (int j = 0; j < 3; j++) acc[i][j] = (f32x4){0.f, 0.f, 0.f, 0.f};

  const float* src = cbuf + (size_t)b * CHW + hw0;
  int boff = (wn * 48 + l15) * 36 + l4 * 8;

  #pragma unroll 1
  for (int icb = 0; icb < 8; ++icb) {
    int ic0 = icb << 5;
    #pragma unroll 4
    for (int idx = tid; idx < 1024; idx += 256) {
      int px = idx & 63, ip = idx >> 6;
      const float* p = src + (size_t)(ic0 + 2 * ip) * HW + px;
      float v0 = p[0], v1 = p[HW];
      unsigned hp, mp, lp;
      split3pack2(v0, v1, hp, mp, lp);
      int off = px * 36 + 2 * ip;
      *(unsigned*)&xt_h[off] = hp;
      *(unsigned*)&xt_m[off] = mp;
      *(unsigned*)&xt_l[off] = lp;
    }
    __syncthreads();
    const short* bh_base = pnk_h + (size_t)icb * 192 * 36 + boff;
    const short* bm_base = pnk_m + (size_t)icb * 192 * 36 + boff;
    const short* bl_base = pnk_l + (size_t)icb * 192 * 36 + boff;
    bf16x8 ah[4], am[4], al[4];
    #pragma unroll
    for (int mf = 0; mf < 4; ++mf) {
      int off = (mf * 16 + l15) * 36 + l4 * 8;
      ah[mf] = ldfrag(xt_h + off);
      am[mf] = ldfrag(xt_m + off);
      al[mf] = ldfrag(xt_l + off);
    }
    #pragma unroll
    for (int nf = 0; nf < 3; ++nf) {
      bf16x8 bh = ldfrag(bh_base + nf * 576);
      #pragma unroll
      for (int mf = 0; mf < 4; ++mf)
        acc[mf][nf] = __builtin_amdgcn_mfma_f32_16x16x32_bf16(ah[mf], bh, acc[mf][nf], 0, 0, 0);
    }
    #pragma unroll
    for (int nf = 0; nf < 3; ++nf) {
      bf16x8 bm = ldfrag(bm_base + nf * 576);
      #pragma unroll
      for (int mf = 0; mf < 4; ++mf)
        acc[mf][nf] = __builtin_amdgcn_mfma_f32_16x16x32_bf16(ah[mf], bm, acc[mf][nf], 0, 0, 0);
    }
    #pragma unroll
    for (int nf = 0; nf < 3; ++nf) {
      bf16x8 bh = ldfrag(bh_base + nf * 576);
      #pragma unroll
      for (int mf = 0; mf < 4; ++mf)
        acc[mf][nf] = __builtin_amdgcn_mfma_f32_16x16x32_bf16(am[mf], bh, acc[mf][nf], 0, 0, 0);
    }
    #pragma unroll
    for (int nf = 0; nf < 3; ++nf) {
      bf16x8 bm = ldfrag(bm_base + nf * 576);
      #pragma unroll
      for (int mf = 0; mf < 4; ++mf)
        acc[mf][nf] = __builtin_amdgcn_mfma_f32_16x16x32_bf16(am[mf], bm, acc[mf][nf], 0, 0, 0);
    }
    #pragma unroll
    for (int nf = 0; nf < 3; ++nf) {
      bf16x8 bl = ldfrag(bl_base + nf * 576);
      #pragma unroll
      for (int mf = 0; mf < 4; ++mf)
        acc[mf][nf] = __builtin_amdgcn_mfma_f32_16x16x32_bf16(ah[mf], bl, acc[mf][nf], 0, 0, 0);
    }
    #pragma unroll
    for (int nf = 0; nf < 3; ++nf) {
      bf16x8 bh = ldfrag(bh_base + nf * 576);
      #pragma unroll
      for (int mf = 0; mf < 4; ++mf)
        acc[mf][nf] = __builtin_amdgcn_mfma_f32_16x16x32_bf16(al[mf], bh, acc[mf][nf], 0, 0, 0);
    }
    __syncthreads();
  }
  size_t n0 = (size_t)b * HW + hw0;
  #pragma unroll
  for (int nf = 0; nf < 3; ++nf) {
    int r = wn * 48 + nf * 16 + l15;
    if (r < RR) {
      #pragma unroll
      for (int mf = 0; mf < 4; ++mf) {
        int px = mf * 16 + l4 * 4;
        #pragma unroll
        for (int rg = 0; rg < 4; ++rg)
          logits[(n0 + px + rg) * RR + r] = acc[mf][nf][rg];
      }
    }
  }
}

// ============ out_seg = LN_k(max_j masks) + pred/correct ============
__global__ __launch_bounds__(256) void k_out(const float* __restrict__ logits,
                                             const int* __restrict__ gt,
                                             const float* __restrict__ mn_g,
                                             const float* __restrict__ mn_b,
                                             float* __restrict__ out_seg,
                                             int* __restrict__ corr) {
  __shared__ float lds[64][193];
  int n0 = blockIdx.x * 64;
  int tid = threadIdx.x;
  for (int idx = tid; idx < 64 * RR; idx += 256) {
    int rr = idx / RR, cc = idx - rr * RR;
    lds[rr][cc] = logits[(size_t)n0 * RR + idx];
  }
  __syncthreads();
  if (tid < 64) {
    int n = n0 + tid;
    float mx[KK];
    float S1 = 0.f, S2 = 0.f;
    #pragma unroll
    for (int k = 0; k < KK; k++) {
      float m_ = lds[tid][k * 10];
      #pragma unroll
      for (int j = 1; j < 10; j++) m_ = fmaxf(m_, lds[tid][k * 10 + j]);
      mx[k] = m_;
      S1 += m_;
      S2 += m_ * m_;
    }
    float mu = S1 * (1.f / 19.f);
    float var = fmaxf(S2 * (1.f / 19.f) - mu * mu, 0.f);
    float inv = 1.f / sqrtf(var + 1e-5f);
    int b = n >> 15, hw = n & 32767;
    float best = -3.4e38f;
    int pred = 0;
    #pragma unroll
    for (int k = 0; k < KK; k++) {
      float o = (mx[k] - mu) * inv * mn_g[k] + mn_b[k];
      out_seg[(size_t)b * 622592 + (size_t)k * 32768 + hw] = o;
      if (o > best) { best = o; pred = k; }
    }
    corr[n] = (gt[n] == pred) ? 1 : 0;
  }
}

// ============ sinkhorn reduction pass: T[k*10+j] += E * b(aprev) ============
__global__ __launch_bounds__(256) void k_sink_sum(const float* __restrict__ logits,
                                                  const int* __restrict__ gt,
                                                  float* __restrict__ Tout,
                                                  const float* __restrict__ aprev) {
  __shared__ float tl[RP];
  int tid = threadIdx.x;
  if (tid < RP) tl[tid] = 0.f;
  __syncthreads();
  int n = blockIdx.x * 256 + tid;
  int k = gt[n];
  const float* lp = logits + (size_t)n * RR + k * 10;
  float e[10];
  #pragma unroll
  for (int j = 0; j < 10; j++) e[j] = expf(lp[j] * 20.0f);
  float bfac = 1.f;
  if (aprev != nullptr) {
    float den = 0.f;
    #pragma unroll
    for (int j = 0; j < 10; j++) den += e[j] * aprev[k * 10 + j];
    bfac = 1.f / fmaxf(den, 1e-30f);
  }
  #pragma unroll
  for (int j = 0; j < 10; j++) atomicAdd(&tl[k * 10 + j], e[j] * bfac);
  __syncthreads();
  if (tid < RR) atomicAdd(&Tout[tid], tl[tid]);
}

__global__ __launch_bounds__(256) void k_calc_a(const float* __restrict__ T,
                                                float* __restrict__ a) {
  int t = threadIdx.x;
  if (t < RR) a[t] = 1.f / (10.f * fmaxf(T[t], 1e-12f));
  else if (t < RP) a[t] = 0.f;
}

// ============ final sinkhorn pass: proto_target, gumbel-hard key, n_cnt ============
__global__ __launch_bounds__(256) void k_final(const float* __restrict__ logits,
                                               const int* __restrict__ gt,
                                               const float* __restrict__ a3,
                                               const float* __restrict__ gu,
                                               const int* __restrict__ corr,
                                               float* __restrict__ tgt,
                                               int* __restrict__ key,
                                               int* __restrict__ ncnt) {
  int n = blockIdx.x * 256 + threadIdx.x;
  int k = gt[n];
  const float* lp = logits + (size_t)n * RR + k * 10;
  float w[10];
  float den = 0.f, bestw = -1.f;
  int idx = 0;
  #pragma unroll
  for (int j = 0; j < 10; j++) {
    w[j] = expf(lp[j] * 20.0f) * a3[k * 10 + j];
    den += w[j];
    if (w[j] > bestw) { bestw = w[j]; idx = j; }
  }
  tgt[n] = (float)(idx + 10 * k);
  float dinv = 1.f / fmaxf(den, 1e-30f);
  const float* gp = gu + ((size_t)k * NN + n) * 10;
  float bestq = -3.4e38f;
  int jh = 0;
  #pragma unroll
  for (int j = 0; j < 10; j++) {
    float g = -logf(-logf(gp[j] + 1e-20f) + 1e-20f);
    float q = w[j] * dinv + g;
    if (q > bestq) { bestq = q; jh = j; }
  }
  int kv = -1;
  if (corr[n]) {
    kv = k * 10 + jh;
    atomicAdd(&ncnt[kv], 1);
  }
  key[n] = kv;
}

// ============ f[k,j,:] += _c[n,:] over counted samples ============
__global__ __launch_bounds__(256) void k_accum_f(const int* __restrict__ key,
                                                 const float* __restrict__ cbuf,
                                                 float* __restrict__ f) {
  __shared__ int ks[64];
  int n0 = blockIdx.x * 64;
  int tid = threadIdx.x;
  if (tid < 64) ks[tid] = key[n0 + tid];
  __syncthreads();
  for (int s = 0; s < 64; s++) {
    int kv = ks[s];
    if (kv >= 0) {
      int n = n0 + s;
      int b = n >> 15, hw = n & 32767;
      atomicAdd(&f[kv * 256 + tid], cbuf[(size_t)b * CHW + (size_t)tid * HW + hw]);
    }
  }
}

// ============ prototype EMA update + renormalize ============
__global__ __launch_bounds__(256) void k_update(const float* __restrict__ Pn,
                                                const float* __restrict__ f,
                                                const int* __restrict__ ncnt,
                                                float* __restrict__ outP) {
  int r = blockIdx.x, d = threadIdx.x;
  int k = r / 10;
  __shared__ float red[256];
  __shared__ int hasS;
  if (d == 0) {
    int s = 0;
    for (int j = 0; j < 10; j++) s += ncnt[k * 10 + j];
    hasS = s;
  }
  __syncthreads();
  bool upd = (ncnt[r] != 0) && (hasS > 0);
  float fv = f[r * 256 + d];
  red[d] = fv * fv;
  __syncthreads();
  #pragma unroll
  for (int s = 128; s > 0; s >>= 1) {
    if (d < s) red[d] += red[d + s];
    __syncthreads();
  }
  float fn2 = red[0];
  __syncthreads();
  float fl = fv / fmaxf(sqrtf(fn2), 1e-12f);
  float p = Pn[r * 256 + d];
  float nv = upd ? (0.999f * p + 0.001f * fl) : p;
  red[d] = nv * nv;
  __syncthreads();
  #pragma unroll
  for (int s = 128; s > 0; s >>= 1) {
    if (d < s) red[d] += red[d + s];
    __syncthreads();
  }
  outP[r * 256 + d] = nv / fmaxf(sqrtf(red[0]), 1e-12f);
}

// ============ launch ============
extern "C" void kernel_launch(void* const* d_in, const int* in_sizes, int n_in,
                              void* d_out, int out_size, void* d_ws, size_t ws_size,
                              hipStream_t stream) {
  const float* x      = (const float*)d_in[0];
  const int*   gt     = (const int*)  d_in[1];
  const float* gu     = (const float*)d_in[2];
  const float* conv_w = (const float*)d_in[3];
  const float* conv_b = (const float*)d_in[4];
  const float* bn1_s  = (const float*)d_in[5];
  const float* bn1_b  = (const float*)d_in[6];
  const float* bn1_m  = (const float*)d_in[7];
  const float* bn1_v  = (const float*)d_in[8];
  const float* pa_w   = (const float*)d_in[9];
  const float* pa_b   = (const float*)d_in[10];
  const float* bn2_s  = (const float*)d_in[11];
  const float* bn2_b  = (const float*)d_in[12];
  const float* bn2_m  = (const float*)d_in[13];
  const float* bn2_v  = (const float*)d_in[14];
  const float* pb_w   = (const float*)d_in[15];
  const float* pb_b   = (const float*)d_in[16];
  const float* fn_g   = (const float*)d_in[17];
  const float* fn_b   = (const float*)d_in[18];
  const float* mn_g   = (const float*)d_in[19];
  const float* mn_b   = (const float*)d_in[20];
  const float* protos = (const float*)d_in[21];

  float* ws  = (float*)d_ws;
  float* out = (float*)d_out;

  float* buf   = ws + WS_BUF;
  short* wpk_h = (short*)(ws + WS_WPK);
  short* wpk_l = wpk_h + 9 * 8 * 256 * 36;
  short* ppa_h = (short*)(ws + WS_PPA);
  short* ppa_m = ppa_h + 8 * 256 * 36;
  short* ppa_l = ppa_h + 2 * 8 * 256 * 36;
  short* ppb_h = (short*)(ws + WS_PPB);
  short* ppb_m = ppb_h + 8 * 256 * 36;
  short* ppb_l = ppb_h + 2 * 8 * 256 * 36;
  float* Pn    = ws + WS_PN;
  short* pnk_h = (short*)(ws + WS_PNK);
  short* pnk_m = pnk_h + 8 * 192 * 36;
  short* pnk_l = pnk_h + 2 * 8 * 192 * 36;
  float* Tarr  = ws + WS_T;
  float* farr  = ws + WS_F;
  float* aarr  = ws + WS_A;
  int*   ncnt  = (int*)(ws + WS_NCNT);
  int*   corr  = (int*)(ws + WS_CORR);
  int*   key   = (int*)(ws + WS_KEY);

  float* logits = out + O_LOG;

  // zero T[576] + f[48640] + a[576] + ncnt[192]  (contiguous region)
  hipMemsetAsync(ws + WS_T, 0, (size_t)(576 + 48640 + 576 + 192) * 4, stream);

  k_prep_protos<<<RP, 256, 0, stream>>>(protos, Pn, pnk_h, pnk_m, pnk_l);
  k_prep_wsplit<<<72, 256, 0, stream>>>(conv_w, wpk_h, wpk_l);
  k_prep_packs<<<16, 256, 0, stream>>>(pa_w, pb_w, ppa_h, ppa_m, ppa_l,
                                       ppb_h, ppb_m, ppb_l);
  k_conv_mfma<<<1024, 256, 0, stream>>>(x, wpk_h, wpk_l, conv_b,
                                        bn1_s, bn1_b, bn1_m, bn1_v, buf);
  k_mlp_mfma<0><<<1024, 256, 0, stream>>>(buf, ppa_h, ppa_m, ppa_l, pa_b,
                                          bn2_s, bn2_b, bn2_m, bn2_v);
  k_mlp_mfma<1><<<1024, 256, 0, stream>>>(buf, ppb_h, ppb_m, ppb_l, pb_b,
                                          fn_g, fn_b, nullptr, nullptr);
  k_masks_mfma<<<2048, 256, 0, stream>>>(buf, pnk_h, pnk_m, pnk_l, logits);
  k_out<<<2048, 256, 0, stream>>>(logits, gt, mn_g, mn_b, out, corr);
  k_sink_sum<<<512, 256, 0, stream>>>(logits, gt, Tarr + 0,   nullptr);
  k_calc_a<<<1, 256, 0, stream>>>(Tarr + 0,   aarr + 0);
  k_sink_sum<<<512, 256, 0, stream>>>(logits, gt, Tarr + 192, aarr + 0);
  k_calc_a<<<1, 256, 0, stream>>>(Tarr + 192, aarr + 192);
  k_sink_sum<<<512, 256, 0, stream>>>(logits, gt, Tarr + 384, aarr + 192);
  k_calc_a<<<1, 256, 0, stream>>>(Tarr + 384, aarr + 384);
  k_final<<<512, 256, 0, stream>>>(logits, gt, aarr + 384, gu, corr, out + O_TGT, key, ncnt);
  k_accum_f<<<2048, 256, 0, stream>>>(key, buf, farr);
  k_update<<<190, 256, 0, stream>>>(Pn, farr, ncnt, out + O_PROTO);

  (void)in_sizes; (void)n_in; (void)out_size; (void)ws_size;
}

// Round 17
// 865.111 us; speedup vs baseline: 1.1078x; 1.0248x over previous
//
#include <hip/hip_runtime.h>
#include <cstddef>
#include <cstdint>

// ---------------- problem constants ----------------
#define BB   4
#define CC   256
#define HHh  128
#define WWi  256
#define HW   32768      // H*W
#define CHW  8388608    // C*H*W
#define NN   131072     // B*H*W
#define KK   19
#define MMp  10
#define RR   190        // K*M
#define RP   192

// ---------------- output offsets (floats) ----------------
#define O_LOG   2490368     // out_seg size = 4*19*128*256
#define O_TGT   27394048
#define O_PROTO 27525120

// ---------------- ws offsets (floats) ----------------
#define WS_BUF   0           // 33,554,432 : y -> z1 -> _c (in-place, [b][c][h][w])
#define WS_WPK   33554432    // 663,552 : conv 2-way split (2 x 663552 shorts)
#define WS_PPA   34217984    // 110,592 : pa 3-way split (3 x 73728 shorts) [icb][oc][36]
#define WS_PPB   34328576    // 110,592 : pb 3-way split
#define WS_PN    34439168    // 48,640  : normalized protos [190][256] f32
#define WS_PNK   34487808    // 82,944  : proto 3-way split (3 x 55296 shorts) [icb][192][36]
#define WS_T     34570752    // 3*192 sinkhorn sums
#define WS_F     34571328    // 48,640 : f accumulator
#define WS_A     34619968    // 3*192 sinkhorn row scales
#define WS_NCNT  34620544    // 192 int
#define WS_CORR  34620736    // 131,072 int
#define WS_KEY   34751808    // 131,072 int
// end = 34,882,880 floats = 139.5 MB

typedef __attribute__((ext_vector_type(8))) short bf16x8;
typedef __attribute__((ext_vector_type(4))) short s16x4;
typedef __attribute__((ext_vector_type(4))) float f32x4;

__device__ __forceinline__ void split2pack(float v0, float v1, unsigned& hp, unsigned& lp) {
  unsigned u0 = __float_as_uint(v0), u1 = __float_as_uint(v1);
  unsigned h0 = u0 & 0xffff0000u, h1 = u1 & 0xffff0000u;
  float r0 = v0 - __uint_as_float(h0);
  float r1 = v1 - __uint_as_float(h1);
  hp = (h0 >> 16) | h1;
  lp = (__float_as_uint(r0) >> 16) | (__float_as_uint(r1) & 0xffff0000u);
}

__device__ __forceinline__ void split1(float v, short& h, short& l) {
  unsigned u = __float_as_uint(v);
  unsigned hm = u & 0xffff0000u;
  float r = v - __uint_as_float(hm);
  h = (short)(hm >> 16);
  l = (short)(__float_as_uint(r) >> 16);
}

__device__ __forceinline__ void split3s(float v, short& h, short& m, short& l) {
  unsigned u = __float_as_uint(v);
  unsigned hm = u & 0xffff0000u;
  float r1 = v - __uint_as_float(hm);
  unsigned mm = __float_as_uint(r1) & 0xffff0000u;
  float r2 = r1 - __uint_as_float(mm);
  h = (short)(hm >> 16);
  m = (short)(mm >> 16);
  l = (short)(__float_as_uint(r2) >> 16);
}

__device__ __forceinline__ void split3pack2(float v0, float v1,
                                            unsigned& hp, unsigned& mp, unsigned& lp) {
  unsigned u0 = __float_as_uint(v0), u1 = __float_as_uint(v1);
  unsigned h0 = u0 & 0xffff0000u, h1 = u1 & 0xffff0000u;
  float r0 = v0 - __uint_as_float(h0);
  float r1 = v1 - __uint_as_float(h1);
  unsigned m0 = __float_as_uint(r0) & 0xffff0000u, m1 = __float_as_uint(r1) & 0xffff0000u;
  float s0 = r0 - __uint_as_float(m0);
  float s1 = r1 - __uint_as_float(m1);
  hp = (h0 >> 16) | h1;
  mp = (m0 >> 16) | m1;
  lp = (__float_as_uint(s0) >> 16) | (__float_as_uint(s1) & 0xffff0000u);
}

__device__ __forceinline__ bf16x8 ldfrag(const short* p) {
  union { bf16x8 v; s16x4 q[2]; } u;
  u.q[0] = *(const s16x4*)p;
  u.q[1] = *(const s16x4*)(p + 4);
  return u.v;
}

// ============ prototype normalize + 3-way split-pack ============
__global__ __launch_bounds__(256) void k_prep_protos(const float* __restrict__ protos,
                                                     float* __restrict__ Pn,
                                                     short* __restrict__ pnk_h,
                                                     short* __restrict__ pnk_m,
                                                     short* __restrict__ pnk_l) {
  int r = blockIdx.x, d = threadIdx.x;
  int icb = d >> 5, i = d & 31;
  int base = (icb * 192 + r) * 36;
  if (r >= RR) {       // zero pad rows 190,191
    pnk_h[base + i] = 0; pnk_m[base + i] = 0; pnk_l[base + i] = 0;
    if (i < 4) { pnk_h[base + 32 + i] = 0; pnk_m[base + 32 + i] = 0; pnk_l[base + 32 + i] = 0; }
    return;
  }
  float v = protos[r * 256 + d];
  __shared__ float red[256];
  red[d] = v * v;
  __syncthreads();
  #pragma unroll
  for (int s = 128; s > 0; s >>= 1) {
    if (d < s) red[d] += red[d + s];
    __syncthreads();
  }
  float inv = 1.f / fmaxf(sqrtf(red[0]), 1e-12f);
  float pv = v * inv;
  Pn[r * 256 + d] = pv;
  short h, m, l;
  split3s(pv, h, m, l);
  pnk_h[base + i] = h; pnk_m[base + i] = m; pnk_l[base + i] = l;
  if (i < 4) { pnk_h[base + 32 + i] = 0; pnk_m[base + 32 + i] = 0; pnk_l[base + 32 + i] = 0; }
}

// ============ conv weight 2-way split-pack ============
__global__ __launch_bounds__(256) void k_prep_wsplit(const float* __restrict__ conv_w,
                                                     short* __restrict__ wpk_h,
                                                     short* __restrict__ wpk_l) {
  int blk = blockIdx.x;             // t9*8 + icb
  int t9 = blk >> 3, icb = blk & 7;
  int oc = threadIdx.x;
  short* dh = wpk_h + ((size_t)blk * 256 + oc) * 36;
  short* dl = wpk_l + ((size_t)blk * 256 + oc) * 36;
  #pragma unroll 4
  for (int i = 0; i < 32; i++) {
    float v = conv_w[((size_t)oc * 256 + icb * 32 + i) * 9 + t9];
    short h, l;
    split1(v, h, l);
    dh[i] = h; dl[i] = l;
  }
  #pragma unroll
  for (int i = 32; i < 36; i++) { dh[i] = 0; dl[i] = 0; }
}

// ============ 1x1 weight 3-way split-pack (pa, pb) ============
__global__ __launch_bounds__(256) void k_prep_packs(const float* __restrict__ pa_w,
                                                    const float* __restrict__ pb_w,
                                                    short* __restrict__ ppa_h,
                                                    short* __restrict__ ppa_m,
                                                    short* __restrict__ ppa_l,
                                                    short* __restrict__ ppb_h,
                                                    short* __restrict__ ppb_m,
                                                    short* __restrict__ ppb_l) {
  int blk = blockIdx.x;
  const float* W;
  short *dh, *dm, *dl;
  int icb;
  if (blk < 8) { icb = blk;     W = pa_w; dh = ppa_h; dm = ppa_m; dl = ppa_l; }
  else         { icb = blk - 8; W = pb_w; dh = ppb_h; dm = ppb_m; dl = ppb_l; }
  int oc = threadIdx.x;
  size_t base = ((size_t)icb * 256 + oc) * 36;
  dh += base; dm += base; dl += base;
  #pragma unroll 4
  for (int i = 0; i < 32; i++) {
    float v = W[(size_t)oc * 256 + icb * 32 + i];
    short h, m, l;
    split3s(v, h, m, l);
    dh[i] = h; dm[i] = m; dl[i] = l;
  }
  #pragma unroll
  for (int i = 32; i < 36; i++) { dh[i] = 0; dm[i] = 0; dl[i] = 0; }
}

// ============ conv3x3 + bias + bn1 + relu : 8-wave occupancy variant ============
// Same 128px x 256oc block tile and identical per-element accumulation chain as
// r14/r16, but split across 8 waves of 64px x 64oc (acc[4][4] = 64 AGPR/wave).
// Single-buffered A (25.9 KB LDS) -> up to 4 blocks/CU = 32 waves/CU for
// latency hiding of the direct-L2 B gather. Bitwise identical output.
__global__ __launch_bounds__(512) void k_conv_mfma(const float* __restrict__ x,
                                                   const short* __restrict__ wpk_h,
                                                   const short* __restrict__ wpk_l,
                                                   const float* __restrict__ conv_b,
                                                   const float* __restrict__ bn_s,
                                                   const float* __restrict__ bn_b,
                                                   const float* __restrict__ bn_m,
                                                   const float* __restrict__ bn_v,
                                                   float* __restrict__ y) {
  int bid = blockIdx.x;
  int tw = bid & 15, th = (bid >> 4) & 15, b = bid >> 8;
  int h0 = th * 8, w0 = tw * 16;
  int tid = threadIdx.x;
  int lane = tid & 63, wv = tid >> 6;     // 8 waves
  int wm = wv & 1, wn = wv >> 1;          // wm: px half (4 rows), wn: oc quarter (64)
  int l15 = lane & 15, l4 = lane >> 4;

  __shared__ short xt_h[10 * 18 * 36];    // single-buffered A, 12.96 KB x2
  __shared__ short xt_l[10 * 18 * 36];

  f32x4 acc[4][4];
  #pragma unroll
  for (int i = 0; i < 4; i++)
    #pragma unroll
    for (int j = 0; j < 4; j++) acc[i][j] = (f32x4){0.f, 0.f, 0.f, 0.f};

  const float* xb = x + (size_t)b * CHW;
  int boff = (wn * 64 + l15) * 36 + l4 * 8;   // per-thread B frag offset in a pack slab

  #pragma unroll 1
  for (int icb = 0; icb < 8; ++icb) {
    int ic0 = icb << 5;
    __syncthreads();   // previous taps done reading xt before overwrite
    // ---- stage A: 10 rows x 18 ww x 16 ic-pairs, split h/l (512 threads) ----
    #pragma unroll 4
    for (int idx = tid; idx < 2880; idx += 512) {
      int ww = idx % 18;
      int t  = idx / 18;
      int r  = t % 10;
      int ip = t / 10;
      int hh = h0 - 1 + r, wg = w0 - 1 + ww;
      float v0 = 0.f, v1 = 0.f;
      if ((unsigned)hh < 128u && (unsigned)wg < 256u) {
        const float* px = xb + (size_t)(ic0 + 2 * ip) * HW + hh * WWi + wg;
        v0 = px[0]; v1 = px[HW];
      }
      unsigned hp, lp;
      split2pack(v0, v1, hp, lp);
      int off = (r * 18 + ww) * 36 + 2 * ip;
      *(unsigned*)&xt_h[off] = hp;
      *(unsigned*)&xt_l[off] = lp;
    }
    __syncthreads();
    // ---- 9 taps, B direct from L2, no intra-chunk barriers ----
    #pragma unroll 1
    for (int kh = 0; kh < 3; ++kh) {
      #pragma unroll 1
      for (int kw = 0; kw < 3; ++kw) {
        int t9 = kh * 3 + kw;
        const short* bh_base = wpk_h + ((size_t)(t9 * 8 + icb) * 256) * 36 + boff;
        const short* bl_base = wpk_l + ((size_t)(t9 * 8 + icb) * 256) * 36 + boff;
        bf16x8 ah[4], al[4];
        #pragma unroll
        for (int mf = 0; mf < 4; ++mf) {
          int off = ((wm * 4 + mf + kh) * 18 + l15 + kw) * 36 + l4 * 8;
          ah[mf] = ldfrag(xt_h + off);
          al[mf] = ldfrag(xt_l + off);
        }
        #pragma unroll
        for (int nf = 0; nf < 4; ++nf) {
          bf16x8 bh = ldfrag(bh_base + nf * 576);
          bf16x8 bl = ldfrag(bl_base + nf * 576);
          #pragma unroll
          for (int mf = 0; mf < 4; ++mf) {
            acc[mf][nf] = __builtin_amdgcn_mfma_f32_16x16x32_bf16(ah[mf], bh, acc[mf][nf], 0, 0, 0);
            acc[mf][nf] = __builtin_amdgcn_mfma_f32_16x16x32_bf16(ah[mf], bl, acc[mf][nf], 0, 0, 0);
            acc[mf][nf] = __builtin_amdgcn_mfma_f32_16x16x32_bf16(al[mf], bh, acc[mf][nf], 0, 0, 0);
          }
        }
      }
    }
  }
  // ---- epilogue: BN + ReLU, store f32x4 along w ----
  float* yb = y + (size_t)b * CHW;
  #pragma unroll
  for (int nf = 0; nf < 4; ++nf) {
    int oc = wn * 64 + nf * 16 + l15;
    float sc = bn_s[oc] / sqrtf(bn_v[oc] + 1e-5f);
    float sh = (conv_b[oc] - bn_m[oc]) * sc + bn_b[oc];
    #pragma unroll
    for (int mf = 0; mf < 4; ++mf) {
      int hr = h0 + wm * 4 + mf;
      int w  = w0 + l4 * 4;
      float4 o;
      o.x = fmaxf(acc[mf][nf][0] * sc + sh, 0.f);
      o.y = fmaxf(acc[mf][nf][1] * sc + sh, 0.f);
      o.z = fmaxf(acc[mf][nf][2] * sc + sh, 0.f);
      o.w = fmaxf(acc[mf][nf][3] * sc + sh, 0.f);
      *(float4*)&yb[(size_t)oc * HW + hr * WWi + w] = o;
    }
  }
}

// ============ 1x1 stages: 3-way split MFMA, static acc, B direct from L2 (r14 proven) ============
// MODE 0: z1 = relu(bn2(pa@y + pa_b))        p0..p3 = bn2 s,b,m,v
// MODE 1: _c = l2n(ln(l2n(pb@z1 + pb_b)))    p0,p1 = fn_g,fn_b
template <int MODE>
__global__ __launch_bounds__(256, 2) void k_mlp_mfma(float* __restrict__ buf,
                                                     const short* __restrict__ pk_h,
                                                     const short* __restrict__ pk_m,
                                                     const short* __restrict__ pk_l,
                                                     const float* __restrict__ bias,
                                                     const float* __restrict__ p0,
                                                     const float* __restrict__ p1,
                                                     const float* __restrict__ p2,
                                                     const float* __restrict__ p3) {
  int bid = blockIdx.x;
  int b = bid >> 8, hw0 = (bid & 255) * 128;
  int tid = threadIdx.x;
  int lane = tid & 63, wv = tid >> 6;
  int wm = wv & 1, wn = wv >> 1;
  int l15 = lane & 15, l4 = lane >> 4;

  __shared__ short xt_h[128 * 36];
  __shared__ short xt_m[128 * 36];
  __shared__ short xt_l[128 * 36];
  __shared__ float redS[2][2][128];

  f32x4 acc[4][8];
  #pragma unroll
  for (int i = 0; i < 4; i++)
    #pragma unroll
    for (int j = 0; j < 8; j++) acc[i][j] = (f32x4){0.f, 0.f, 0.f, 0.f};

  const float* src = buf + (size_t)b * CHW + hw0;
  int boff = (wn * 128 + l15) * 36 + l4 * 8;

  #pragma unroll 1
  for (int icb = 0; icb < 8; ++icb) {
    int ic0 = icb << 5;
    #pragma unroll 4
    for (int idx = tid; idx < 2048; idx += 256) {
      int px = idx & 127, ip = idx >> 7;
      const float* p = src + (size_t)(ic0 + 2 * ip) * HW + px;
      float v0 = p[0], v1 = p[HW];
      unsigned hp, mp, lp;
      split3pack2(v0, v1, hp, mp, lp);
      int off = px * 36 + 2 * ip;
      *(unsigned*)&xt_h[off] = hp;
      *(unsigned*)&xt_m[off] = mp;
      *(unsigned*)&xt_l[off] = lp;
    }
    __syncthreads();
    const short* bh_base = pk_h + (size_t)icb * 256 * 36 + boff;
    const short* bm_base = pk_m + (size_t)icb * 256 * 36 + boff;
    const short* bl_base = pk_l + (size_t)icb * 256 * 36 + boff;
    bf16x8 ah[4], am[4], al[4];
    #pragma unroll
    for (int mf = 0; mf < 4; ++mf) {
      int off = (wm * 64 + mf * 16 + l15) * 36 + l4 * 8;
      ah[mf] = ldfrag(xt_h + off);
      am[mf] = ldfrag(xt_m + off);
      al[mf] = ldfrag(xt_l + off);
    }
    // term passes: hh, hm, mh, mm, hl, lh
    #pragma unroll
    for (int nf = 0; nf < 8; ++nf) {
      bf16x8 bh = ldfrag(bh_base + nf * 576);
      #pragma unroll
      for (int mf = 0; mf < 4; ++mf)
        acc[mf][nf] = __builtin_amdgcn_mfma_f32_16x16x32_bf16(ah[mf], bh, acc[mf][nf], 0, 0, 0);
    }
    #pragma unroll
    for (int nf = 0; nf < 8; ++nf) {
      bf16x8 bm = ldfrag(bm_base + nf * 576);
      #pragma unroll
      for (int mf = 0; mf < 4; ++mf)
        acc[mf][nf] = __builtin_amdgcn_mfma_f32_16x16x32_bf16(ah[mf], bm, acc[mf][nf], 0, 0, 0);
    }
    #pragma unroll
    for (int nf = 0; nf < 8; ++nf) {
      bf16x8 bh = ldfrag(bh_base + nf * 576);
      #pragma unroll
      for (int mf = 0; mf < 4; ++mf)
        acc[mf][nf] = __builtin_amdgcn_mfma_f32_16x16x32_bf16(am[mf], bh, acc[mf][nf], 0, 0, 0);
    }
    #pragma unroll
    for (int nf = 0; nf < 8; ++nf) {
      bf16x8 bm = ldfrag(bm_base + nf * 576);
      #pragma unroll
      for (int mf = 0; mf < 4; ++mf)
        acc[mf][nf] = __builtin_amdgcn_mfma_f32_16x16x32_bf16(am[mf], bm, acc[mf][nf], 0, 0, 0);
    }
    #pragma unroll
    for (int nf = 0; nf < 8; ++nf) {
      bf16x8 bl = ldfrag(bl_base + nf * 576);
      #pragma unroll
      for (int mf = 0; mf < 4; ++mf)
        acc[mf][nf] = __builtin_amdgcn_mfma_f32_16x16x32_bf16(ah[mf], bl, acc[mf][nf], 0, 0, 0);
    }
    #pragma unroll
    for (int nf = 0; nf < 8; ++nf) {
      bf16x8 bh = ldfrag(bh_base + nf * 576);
      #pragma unroll
      for (int mf = 0; mf < 4; ++mf)
        acc[mf][nf] = __builtin_amdgcn_mfma_f32_16x16x32_bf16(al[mf], bh, acc[mf][nf], 0, 0, 0);
    }
    __syncthreads();
  }

  float* dst = buf + (size_t)b * CHW + hw0;

  if (MODE == 0) {
    #pragma unroll
    for (int nf = 0; nf < 8; ++nf) {
      int oc = wn * 128 + nf * 16 + l15;
      float sc = p0[oc] / sqrtf(p3[oc] + 1e-5f);
      float sh = (bias[oc] - p2[oc]) * sc + p1[oc];
      #pragma unroll
      for (int mf = 0; mf < 4; ++mf) {
        float4 o;
        o.x = fmaxf(acc[mf][nf][0] * sc + sh, 0.f);
        o.y = fmaxf(acc[mf][nf][1] * sc + sh, 0.f);
        o.z = fmaxf(acc[mf][nf][2] * sc + sh, 0.f);
        o.w = fmaxf(acc[mf][nf][3] * sc + sh, 0.f);
        *(float4*)&dst[(size_t)oc * HW + wm * 64 + mf * 16 + l4 * 4] = o;
      }
    }
  } else {
    float bzv[8], gv[8], btv[8];
    #pragma unroll
    for (int nf = 0; nf < 8; ++nf) {
      int oc = wn * 128 + nf * 16 + l15;
      bzv[nf] = bias[oc];
      gv[nf] = p0[oc];
      btv[nf] = p1[oc];
    }
    float s1[4][4], s2[4][4];
    #pragma unroll
    for (int mf = 0; mf < 4; ++mf)
      #pragma unroll
      for (int rg = 0; rg < 4; ++rg) { s1[mf][rg] = 0.f; s2[mf][rg] = 0.f; }
    #pragma unroll
    for (int nf = 0; nf < 8; ++nf)
      #pragma unroll
      for (int mf = 0; mf < 4; ++mf)
        #pragma unroll
        for (int rg = 0; rg < 4; ++rg) {
          float z = acc[mf][nf][rg] + bzv[nf];
          acc[mf][nf][rg] = z;
          s1[mf][rg] += z;
          s2[mf][rg] += z * z;
        }
    #pragma unroll
    for (int mf = 0; mf < 4; ++mf)
      #pragma unroll
      for (int rg = 0; rg < 4; ++rg) {
        #pragma unroll
        for (int m = 1; m < 16; m <<= 1) {
          s1[mf][rg] += __shfl_xor(s1[mf][rg], m, 64);
          s2[mf][rg] += __shfl_xor(s2[mf][rg], m, 64);
        }
      }
    if (l15 == 0) {
      #pragma unroll
      for (int mf = 0; mf < 4; ++mf)
        #pragma unroll
        for (int rg = 0; rg < 4; ++rg) {
          int pxl = wm * 64 + mf * 16 + l4 * 4 + rg;
          redS[0][wn][pxl] = s1[mf][rg];
          redS[1][wn][pxl] = s2[mf][rg];
        }
    }
    __syncthreads();
    float s3[4][4];
    #pragma unroll
    for (int mf = 0; mf < 4; ++mf)
      #pragma unroll
      for (int rg = 0; rg < 4; ++rg) {
        int pxl = wm * 64 + mf * 16 + l4 * 4 + rg;
        float S1 = redS[0][0][pxl] + redS[0][1][pxl];
        float S2 = redS[1][0][pxl] + redS[1][1][pxl];
        float iv = 1.f / fmaxf(sqrtf(S2), 1e-12f);
        float mu = S1 * iv * (1.f / 256.f);
        float eu2 = S2 * iv * iv * (1.f / 256.f);
        float var = fmaxf(eu2 - mu * mu, 0.f);
        float rq = 1.f / sqrtf(var + 1e-5f);
        float s3loc = 0.f;
        #pragma unroll
        for (int nf = 0; nf < 8; ++nf) {
          float v = (acc[mf][nf][rg] * iv - mu) * rq * gv[nf] + btv[nf];
          acc[mf][nf][rg] = v;
          s3loc += v * v;
        }
        s3[mf][rg] = s3loc;
      }
    #pragma unroll
    for (int mf = 0; mf < 4; ++mf)
      #pragma unroll
      for (int rg = 0; rg < 4; ++rg) {
        #pragma unroll
        for (int m = 1; m < 16; m <<= 1)
          s3[mf][rg] += __shfl_xor(s3[mf][rg], m, 64);
      }
    __syncthreads();
    if (l15 == 0) {
      #pragma unroll
      for (int mf = 0; mf < 4; ++mf)
        #pragma unroll
        for (int rg = 0; rg < 4; ++rg) {
          int pxl = wm * 64 + mf * 16 + l4 * 4 + rg;
          redS[0][wn][pxl] = s3[mf][rg];
        }
    }
    __syncthreads();
    float cinv[4][4];
    #pragma unroll
    for (int mf = 0; mf < 4; ++mf)
      #pragma unroll
      for (int rg = 0; rg < 4; ++rg) {
        int pxl = wm * 64 + mf * 16 + l4 * 4 + rg;
        cinv[mf][rg] = 1.f / fmaxf(sqrtf(redS[0][0][pxl] + redS[0][1][pxl]), 1e-12f);
      }
    #pragma unroll
    for (int nf = 0; nf < 8; ++nf) {
      int oc = wn * 128 + nf * 16 + l15;
      #pragma unroll
      for (int mf = 0; mf < 4; ++mf) {
        float4 o;
        o.x = acc[mf][nf][0] * cinv[mf][0];
        o.y = acc[mf][nf][1] * cinv[mf][1];
        o.z = acc[mf][nf][2] * cinv[mf][2];
        o.w = acc[mf][nf][3] * cinv[mf][3];
        *(float4*)&dst[(size_t)oc * HW + wm * 64 + mf * 16 + l4 * 4] = o;
      }
    }
  }
}

// ============ masks GEMM: 64px x 192r, 3-way split MFMA, B direct from L2 (r14 proven) ============
__global__ __launch_bounds__(256, 2) void k_masks_mfma(const float* __restrict__ cbuf,
                                                       const short* __restrict__ pnk_h,
                                                       const short* __restrict__ pnk_m,
                                                       const short* __restrict__ pnk_l,
                                                       float* __restrict__ logits) {
  int bid = blockIdx.x;
  int b = bid >> 9, hw0 = (bid & 511) * 64;
  int tid = threadIdx.x;
  int lane = tid & 63, wn = tid >> 6;
  int l15 = lane & 15, l4 = lane >> 4;

  __shared__ short xt_h[64 * 36];
  __shared__ short xt_m[64 * 36];
  __shared__ short xt_l[64 * 36];

  f32x4 acc[4][3];
  #pragma unroll
  for (int i = 0; i < 4; i++)
    #pragma unroll
    for (int j = 0; j < 3; j++) acc[i][j] = (f32x4){0.f, 0.f, 0.f, 0.f};

  const float* src = cbuf + (size_t)b * CHW + hw0;
  int boff = (wn * 48 + l15) * 36 + l4 * 8;

  #pragma unroll 1
  for (int icb = 0; icb < 8; ++icb) {
    int ic0 = icb << 5;
    #pragma unroll 4
    for (int idx = tid; idx < 1024; idx += 256) {
      int px = idx & 63, ip = idx >> 6;
      const float* p = src + (size_t)(ic0 + 2 * ip) * HW + px;
      float v0 = p[0], v1 = p[HW];
      unsigned hp, mp, lp;
      split3pack2(v0, v1, hp, mp, lp);
      int off = px * 36 + 2 * ip;
      *(unsigned*)&xt_h[off] = hp;
      *(unsigned*)&xt_m[off] = mp;
      *(unsigned*)&xt_l[off] = lp;
    }
    __syncthreads();
    const short* bh_base = pnk_h + (size_t)icb * 192 * 36 + boff;
    const short* bm_base = pnk_m + (size_t)icb * 192 * 36 + boff;
    const short* bl_base = pnk_l + (size_t)icb * 192 * 36 + boff;
    bf16x8 ah[4], am[4], al[4];
    #pragma unroll
    for (int mf = 0; mf < 4; ++mf) {
      int off = (mf * 16 + l15) * 36 + l4 * 8;
      ah[mf] = ldfrag(xt_h + off);
      am[mf] = ldfrag(xt_m + off);
      al[mf] = ldfrag(xt_l + off);
    }
    #pragma unroll
    for (int nf = 0; nf < 3; ++nf) {
      bf16x8 bh = ldfrag(bh_base + nf * 576);
      #pragma unroll
      for (int mf = 0; mf < 4; ++mf)
        acc[mf][nf] = __builtin_amdgcn_mfma_f32_16x16x32_bf16(ah[mf], bh, acc[mf][nf], 0, 0, 0);
    }
    #pragma unroll
    for (int nf = 0; nf < 3; ++nf) {
      bf16x8 bm = ldfrag(bm_base + nf * 576);
      #pragma unroll
      for (int mf = 0; mf < 4; ++mf)
        acc[mf][nf] = __builtin_amdgcn_mfma_f32_16x16x32_bf16(ah[mf], bm, acc[mf][nf], 0, 0, 0);
    }
    #pragma unroll
    for (int nf = 0; nf < 3; ++nf) {
      bf16x8 bh = ldfrag(bh_base + nf * 576);
      #pragma unroll
      for (int mf = 0; mf < 4; ++mf)
        acc[mf][nf] = __builtin_amdgcn_mfma_f32_16x16x32_bf16(am[mf], bh, acc[mf][nf], 0, 0, 0);
    }
    #pragma unroll
    for (int nf = 0; nf < 3; ++nf) {
      bf16x8 bm = ldfrag(bm_base + nf * 576);
      #pragma unroll
      for (int mf = 0; mf < 4; ++mf)
        acc[mf][nf] = __builtin_amdgcn_mfma_f32_16x16x32_bf16(am[mf], bm, acc[mf][nf], 0, 0, 0);
    }
    #pragma unroll
    for (int nf = 0; nf < 3; ++nf) {
      bf16x8 bl = ldfrag(bl_base + nf * 576);
      #pragma unroll
      for (int mf = 0; mf < 4; ++mf)
        acc[mf][nf] = __builtin_amdgcn_mfma_f32_16x16x32_bf16(ah[mf], bl, acc[mf][nf], 0, 0, 0);
    }
    #pragma unroll
    for (int nf = 0; nf < 3; ++nf) {
      bf16x8 bh = ldfrag(bh_base + nf * 576);
      #pragma unroll
      for (int mf = 0; mf < 4; ++mf)
        acc[mf][nf] = __builtin_amdgcn_mfma_f32_16x16x32_bf16(al[mf], bh, acc[mf][nf], 0, 0, 0);
    }
    __syncthreads();
  }
  size_t n0 = (size_t)b * HW + hw0;
  #pragma unroll
  for (int nf = 0; nf < 3; ++nf) {
    int r = wn * 48 + nf * 16 + l15;
    if (r < RR) {
      #pragma unroll
      for (int mf = 0; mf < 4; ++mf) {
        int px = mf * 16 + l4 * 4;
        #pragma unroll
        for (int rg = 0; rg < 4; ++rg)
          logits[(n0 + px + rg) * RR + r] = acc[mf][nf][rg];
      }
    }
  }
}

// ============ out_seg = LN_k(max_j masks) + pred/correct ============
__global__ __launch_bounds__(256) void k_out(const float* __restrict__ logits,
                                             const int* __restrict__ gt,
                                             const float* __restrict__ mn_g,
                                             const float* __restrict__ mn_b,
                                             float* __restrict__ out_seg,
                                             int* __restrict__ corr) {
  __shared__ float lds[64][193];
  int n0 = blockIdx.x * 64;
  int tid = threadIdx.x;
  for (int idx = tid; idx < 64 * RR; idx += 256) {
    int rr = idx / RR, cc = idx - rr * RR;
    lds[rr][cc] = logits[(size_t)n0 * RR + idx];
  }
  __syncthreads();
  if (tid < 64) {
    int n = n0 + tid;
    float mx[KK];
    float S1 = 0.f, S2 = 0.f;
    #pragma unroll
    for (int k = 0; k < KK; k++) {
      float m_ = lds[tid][k * 10];
      #pragma unroll
      for (int j = 1; j < 10; j++) m_ = fmaxf(m_, lds[tid][k * 10 + j]);
      mx[k] = m_;
      S1 += m_;
      S2 += m_ * m_;
    }
    float mu = S1 * (1.f / 19.f);
    float var = fmaxf(S2 * (1.f / 19.f) - mu * mu, 0.f);
    float inv = 1.f / sqrtf(var + 1e-5f);
    int b = n >> 15, hw = n & 32767;
    float best = -3.4e38f;
    int pred = 0;
    #pragma unroll
    for (int k = 0; k < KK; k++) {
      float o = (mx[k] - mu) * inv * mn_g[k] + mn_b[k];
      out_seg[(size_t)b * 622592 + (size_t)k * 32768 + hw] = o;
      if (o > best) { best = o; pred = k; }
    }
    corr[n] = (gt[n] == pred) ? 1 : 0;
  }
}

// ============ sinkhorn reduction pass: T[k*10+j] += E * b(aprev) ============
__global__ __launch_bounds__(256) void k_sink_sum(const float* __restrict__ logits,
                                                  const int* __restrict__ gt,
                                                  float* __restrict__ Tout,
                                                  const float* __restrict__ aprev) {
  __shared__ float tl[RP];
  int tid = threadIdx.x;
  if (tid < RP) tl[tid] = 0.f;
  __syncthreads();
  int n = blockIdx.x * 256 + tid;
  int k = gt[n];
  const float* lp = logits + (size_t)n * RR + k * 10;
  float e[10];
  #pragma unroll
  for (int j = 0; j < 10; j++) e[j] = expf(lp[j] * 20.0f);
  float bfac = 1.f;
  if (aprev != nullptr) {
    float den = 0.f;
    #pragma unroll
    for (int j = 0; j < 10; j++) den += e[j] * aprev[k * 10 + j];
    bfac = 1.f / fmaxf(den, 1e-30f);
  }
  #pragma unroll
  for (int j = 0; j < 10; j++) atomicAdd(&tl[k * 10 + j], e[j] * bfac);
  __syncthreads();
  if (tid < RR) atomicAdd(&Tout[tid], tl[tid]);
}

__global__ __launch_bounds__(256) void k_calc_a(const float* __restrict__ T,
                                                float* __restrict__ a) {
  int t = threadIdx.x;
  if (t < RR) a[t] = 1.f / (10.f * fmaxf(T[t], 1e-12f));
  else if (t < RP) a[t] = 0.f;
}

// ============ final sinkhorn pass: proto_target, gumbel-hard key, n_cnt ============
__global__ __launch_bounds__(256) void k_final(const float* __restrict__ logits,
                                               const int* __restrict__ gt,
                                               const float* __restrict__ a3,
                                               const float* __restrict__ gu,
                                               const int* __restrict__ corr,
                                               float* __restrict__ tgt,
                                               int* __restrict__ key,
                                               int* __restrict__ ncnt) {
  int n = blockIdx.x * 256 + threadIdx.x;
  int k = gt[n];
  const float* lp = logits + (size_t)n * RR + k * 10;
  float w[10];
  float den = 0.f, bestw = -1.f;
  int idx = 0;
  #pragma unroll
  for (int j = 0; j < 10; j++) {
    w[j] = expf(lp[j] * 20.0f) * a3[k * 10 + j];
    den += w[j];
    if (w[j] > bestw) { bestw = w[j]; idx = j; }
  }
  tgt[n] = (float)(idx + 10 * k);
  float dinv = 1.f / fmaxf(den, 1e-30f);
  const float* gp = gu + ((size_t)k * NN + n) * 10;
  float bestq = -3.4e38f;
  int jh = 0;
  #pragma unroll
  for (int j = 0; j < 10; j++) {
    float g = -logf(-logf(gp[j] + 1e-20f) + 1e-20f);
    float q = w[j] * dinv + g;
    if (q > bestq) { bestq = q; jh = j; }
  }
  int kv = -1;
  if (corr[n]) {
    kv = k * 10 + jh;
    atomicAdd(&ncnt[kv], 1);
  }
  key[n] = kv;
}

// ============ f[k,j,:] += _c[n,:] over counted samples ============
__global__ __launch_bounds__(256) void k_accum_f(const int* __restrict__ key,
                                                 const float* __restrict__ cbuf,
                                                 float* __restrict__ f) {
  __shared__ int ks[64];
  int n0 = blockIdx.x * 64;
  int tid = threadIdx.x;
  if (tid < 64) ks[tid] = key[n0 + tid];
  __syncthreads();
  for (int s = 0; s < 64; s++) {
    int kv = ks[s];
    if (kv >= 0) {
      int n = n0 + s;
      int b = n >> 15, hw = n & 32767;
      atomicAdd(&f[kv * 256 + tid], cbuf[(size_t)b * CHW + (size_t)tid * HW + hw]);
    }
  }
}

// ============ prototype EMA update + renormalize ============
__global__ __launch_bounds__(256) void k_update(const float* __restrict__ Pn,
                                                const float* __restrict__ f,
                                                const int* __restrict__ ncnt,
                                                float* __restrict__ outP) {
  int r = blockIdx.x, d = threadIdx.x;
  int k = r / 10;
  __shared__ float red[256];
  __shared__ int hasS;
  if (d == 0) {
    int s = 0;
    for (int j = 0; j < 10; j++) s += ncnt[k * 10 + j];
    hasS = s;
  }
  __syncthreads();
  bool upd = (ncnt[r] != 0) && (hasS > 0);
  float fv = f[r * 256 + d];
  red[d] = fv * fv;
  __syncthreads();
  #pragma unroll
  for (int s = 128; s > 0; s >>= 1) {
    if (d < s) red[d] += red[d + s];
    __syncthreads();
  }
  float fn2 = red[0];
  __syncthreads();
  float fl = fv / fmaxf(sqrtf(fn2), 1e-12f);
  float p = Pn[r * 256 + d];
  float nv = upd ? (0.999f * p + 0.001f * fl) : p;
  red[d] = nv * nv;
  __syncthreads();
  #pragma unroll
  for (int s = 128; s > 0; s >>= 1) {
    if (d < s) red[d] += red[d + s];
    __syncthreads();
  }
  outP[r * 256 + d] = nv / fmaxf(sqrtf(red[0]), 1e-12f);
}

// ============ launch ============
extern "C" void kernel_launch(void* const* d_in, const int* in_sizes, int n_in,
                              void* d_out, int out_size, void* d_ws, size_t ws_size,
                              hipStream_t stream) {
  const float* x      = (const float*)d_in[0];
  const int*   gt     = (const int*)  d_in[1];
  const float* gu     = (const float*)d_in[2];
  const float* conv_w = (const float*)d_in[3];
  const float* conv_b = (const float*)d_in[4];
  const float* bn1_s  = (const float*)d_in[5];
  const float* bn1_b  = (const float*)d_in[6];
  const float* bn1_m  = (const float*)d_in[7];
  const float* bn1_v  = (const float*)d_in[8];
  const float* pa_w   = (const float*)d_in[9];
  const float* pa_b   = (const float*)d_in[10];
  const float* bn2_s  = (const float*)d_in[11];
  const float* bn2_b  = (const float*)d_in[12];
  const float* bn2_m  = (const float*)d_in[13];
  const float* bn2_v  = (const float*)d_in[14];
  const float* pb_w   = (const float*)d_in[15];
  const float* pb_b   = (const float*)d_in[16];
  const float* fn_g   = (const float*)d_in[17];
  const float* fn_b   = (const float*)d_in[18];
  const float* mn_g   = (const float*)d_in[19];
  const float* mn_b   = (const float*)d_in[20];
  const float* protos = (const float*)d_in[21];

  float* ws  = (float*)d_ws;
  float* out = (float*)d_out;

  float* buf   = ws + WS_BUF;
  short* wpk_h = (short*)(ws + WS_WPK);
  short* wpk_l = wpk_h + 9 * 8 * 256 * 36;
  short* ppa_h = (short*)(ws + WS_PPA);
  short* ppa_m = ppa_h + 8 * 256 * 36;
  short* ppa_l = ppa_h + 2 * 8 * 256 * 36;
  short* ppb_h = (short*)(ws + WS_PPB);
  short* ppb_m = ppb_h + 8 * 256 * 36;
  short* ppb_l = ppb_h + 2 * 8 * 256 * 36;
  float* Pn    = ws + WS_PN;
  short* pnk_h = (short*)(ws + WS_PNK);
  short* pnk_m = pnk_h + 8 * 192 * 36;
  short* pnk_l = pnk_h + 2 * 8 * 192 * 36;
  float* Tarr  = ws + WS_T;
  float* farr  = ws + WS_F;
  float* aarr  = ws + WS_A;
  int*   ncnt  = (int*)(ws + WS_NCNT);
  int*   corr  = (int*)(ws + WS_CORR);
  int*   key   = (int*)(ws + WS_KEY);

  float* logits = out + O_LOG;

  // zero T[576] + f[48640] + a[576] + ncnt[192]  (contiguous region)
  hipMemsetAsync(ws + WS_T, 0, (size_t)(576 + 48640 + 576 + 192) * 4, stream);

  k_prep_protos<<<RP, 256, 0, stream>>>(protos, Pn, pnk_h, pnk_m, pnk_l);
  k_prep_wsplit<<<72, 256, 0, stream>>>(conv_w, wpk_h, wpk_l);
  k_prep_packs<<<16, 256, 0, stream>>>(pa_w, pb_w, ppa_h, ppa_m, ppa_l,
                                       ppb_h, ppb_m, ppb_l);
  k_conv_mfma<<<1024, 512, 0, stream>>>(x, wpk_h, wpk_l, conv_b,
                                        bn1_s, bn1_b, bn1_m, bn1_v, buf);
  k_mlp_mfma<0><<<1024, 256, 0, stream>>>(buf, ppa_h, ppa_m, ppa_l, pa_b,
                                          bn2_s, bn2_b, bn2_m, bn2_v);
  k_mlp_mfma<1><<<1024, 256, 0, stream>>>(buf, ppb_h, ppb_m, ppb_l, pb_b,
                                          fn_g, fn_b, nullptr, nullptr);
  k_masks_mfma<<<2048, 256, 0, stream>>>(buf, pnk_h, pnk_m, pnk_l, logits);
  k_out<<<2048, 256, 0, stream>>>(logits, gt, mn_g, mn_b, out, corr);
  k_sink_sum<<<512, 256, 0, stream>>>(logits, gt, Tarr + 0,   nullptr);
  k_calc_a<<<1, 256, 0, stream>>>(Tarr + 0,   aarr + 0);
  k_sink_sum<<<512, 256, 0, stream>>>(logits, gt, Tarr + 192, aarr + 0);
  k_calc_a<<<1, 256, 0, stream>>>(Tarr + 192, aarr + 192);
  k_sink_sum<<<512, 256, 0, stream>>>(logits, gt, Tarr + 384, aarr + 192);
  k_calc_a<<<1, 256, 0, stream>>>(Tarr + 384, aarr + 384);
  k_final<<<512, 256, 0, stream>>>(logits, gt, aarr + 384, gu, corr, out + O_TGT, key, ncnt);
  k_accum_f<<<2048, 256, 0, stream>>>(key, buf, farr);
  k_update<<<190, 256, 0, stream>>>(Pn, farr, ncnt, out + O_PROTO);

  (void)in_sizes; (void)n_in; (void)out_size; (void)ws_size;
}